// Round 9
// baseline (402.415 us; speedup 1.0000x reference)
//
#include <hip/hip_runtime.h>
#include <hip/hip_bf16.h>

// B=32, C=3, H=W=128, D=512, K=512, S=4, NPOS=32768
#define NPOS 32768
#define EPS_GAP 4e-3f
#define MAXSUS 4096

typedef __attribute__((ext_vector_type(8))) short short8;
typedef __attribute__((ext_vector_type(4))) float floatx4;

static __device__ __forceinline__ float bfu(unsigned short h) {
    return __uint_as_float(((unsigned int)h) << 16);
}
static __device__ __forceinline__ unsigned short f2bf(float f) {
    unsigned int u = __float_as_uint(f);
    u = (u + 0x7fffu + ((u >> 16) & 1u)) >> 16;   // RNE
    return (unsigned short)u;
}
static __device__ __forceinline__ float ldin(const void* p, size_t i, int flag) {
    return flag ? bfu(((const unsigned short*)p)[i]) : ((const float*)p)[i];
}

// LDS-only barrier: drains ds ops (lgkmcnt) but leaves global loads/stores
// in flight across the barrier (no vmcnt(0) drain).
static __device__ __forceinline__ void ldsbar() {
    asm volatile("s_waitcnt lgkmcnt(0)" ::: "memory");
    __builtin_amdgcn_s_barrier();
    asm volatile("" ::: "memory");
}

// Swizzled B-fragment offset (units: shorts). Element (code k, dim d) lands at
// the position the MFMA lane-load wants: fragment(chunk=d>>5, codeTile=k>>4)
// is 64 lanes x 8 shorts contiguous; lane = ((d>>3)&3)*16 + (k&15), sub = d&7.
static __device__ __forceinline__ size_t swzoff(int k, int d) {
    return (size_t)(d >> 5) * 16384 + (size_t)(k >> 4) * 512
         + (size_t)((((d >> 3) & 3) * 16 + (k & 15)) * 8) + (d & 7);
}

// ---------------------------------------------------------------------------
// Sniff: decide bf16 vs fp32 input encoding from codebook column norms.
// ---------------------------------------------------------------------------
__global__ __launch_bounds__(1024) void k_sniff(const void* __restrict__ cb,
                                                int* __restrict__ flag,
                                                int* __restrict__ scnt) {
    __shared__ float s[1024];
    const int t = threadIdx.x;
    const int k = t & 63, g = t >> 6;          // 16 groups x 32 d
    const unsigned short* u = (const unsigned short*)cb;
    float acc = 0.f;
    for (int d = g * 32; d < g * 32 + 32; ++d) {
        float v = bfu(u[(size_t)d * 512 + k]);
        acc = fmaf(v, v, acc);
    }
    s[t] = acc;
    __syncthreads();
    if (t < 64) {
        float a = 0.f;
        #pragma unroll
        for (int g2 = 0; g2 < 16; ++g2) a += s[g2 * 64 + k];
        int ok = (a >= 100.f && a <= 2000.f) ? 1 : 0;
        unsigned long long m = __ballot(ok);
        if (k == 0) {
            *flag = (m == ~0ull) ? 1 : 0;
            *scnt = 0;
        }
    }
}

// ---------------------------------------------------------------------------
// FUSED prep: one launch, role-split by blockIdx. NO cross-role dependencies.
// ---------------------------------------------------------------------------
__global__ __launch_bounds__(256) void k_prepAll(
        const void* __restrict__ We, const void* __restrict__ be,
        const void* __restrict__ Wd, const void* __restrict__ bd,
        const void* __restrict__ cb, const int* __restrict__ flagp,
        float* __restrict__ cWe, float* __restrict__ cbe,
        float* __restrict__ cWd, float* __restrict__ cbd,
        float* __restrict__ cbT, unsigned short* __restrict__ cbHS,
        unsigned short* __restrict__ cbLS,
        float* __restrict__ w2, double* __restrict__ w2d,
        float* __restrict__ U) {
    __shared__ float tile[64][65];
    __shared__ double sd[256];
    const int bid = blockIdx.x;
    const int t = threadIdx.x;
    const int flag = *flagp;

    if (bid < 195) {
        // ---- canonW ----
        int e = bid * 256 + t;
        if (e < 24576)       cWe[e]         = ldin(We, e, flag);
        else if (e < 25088)  cbe[e - 24576] = ldin(be, e - 24576, flag);
        else if (e < 49664)  cWd[e - 25088] = ldin(Wd, e - 25088, flag);
        else if (e < 49667)  cbd[e - 49664] = ldin(bd, e - 49664, flag);
    } else if (bid < 259) {
        // ---- prepcb ----
        const int bb = bid - 195;
        const int D0 = (bb >> 3) * 64, K0 = (bb & 7) * 64;
        for (int it = 0; it < 16; ++it) {
            int r = (t >> 6) + 4 * it, c = t & 63;
            tile[r][c] = ldin(cb, (size_t)(D0 + r) * 512 + K0 + c, flag);
        }
        __syncthreads();
        for (int it = 0; it < 16; ++it) {
            int r = (t >> 6) + 4 * it, c = t & 63;
            float v = tile[c][r];
            int k = K0 + r, d = D0 + c;
            cbT[(size_t)k * 512 + d] = v;
            size_t o2 = swzoff(k, d);
            unsigned short h = f2bf(v);
            cbHS[o2] = h;
            cbLS[o2] = f2bf(v - bfu(h));
        }
    } else if (bid < 267) {
        // ---- w2 ----
        const int k = (bid - 259) * 64 + (t & 63);
        const int g = t >> 6;                  // 4 groups x 128 d
        double acc = 0.0;
        for (int d = g * 128; d < g * 128 + 128; ++d) {
            double v = (double)ldin(cb, (size_t)d * 512 + k, flag);
            acc += v * v;
        }
        sd[t] = acc;
        __syncthreads();
        if (t < 64) {
            double a = sd[t] + sd[t + 64] + sd[t + 128] + sd[t + 192];
            w2[k] = (float)a;
            w2d[k] = a;
        }
    } else {
        // ---- udec: U[k][c*16+u*4+v] = sum_d cb[d][k]*Wd[c][d][3-u][3-v]+bd[c]
        const int kk = (bid - 267) * 4 + (t >> 6);
        const int lane = t & 63;
        const int j = lane >> 2, dpart = lane & 3;
        const int u = (j >> 2) & 3, v = j & 3;
        int woff[3];
        #pragma unroll
        for (int m = 0; m < 3; ++m) woff[m] = m * 8192 + (3 - u) * 4 + (3 - v);
        float a0 = 0.f, a1 = 0.f, a2 = 0.f;
        for (int i = 0; i < 128; ++i) {
            int d = dpart * 128 + i;
            float cw = ldin(cb, (size_t)d * 512 + kk, flag);
            a0 = fmaf(cw, ldin(Wd, (size_t)(woff[0] + d * 16), flag), a0);
            a1 = fmaf(cw, ldin(Wd, (size_t)(woff[1] + d * 16), flag), a1);
            a2 = fmaf(cw, ldin(Wd, (size_t)(woff[2] + d * 16), flag), a2);
        }
        a0 += __shfl_xor(a0, 1); a0 += __shfl_xor(a0, 2);
        a1 += __shfl_xor(a1, 1); a1 += __shfl_xor(a1, 2);
        a2 += __shfl_xor(a2, 1); a2 += __shfl_xor(a2, 2);
        if (dpart == 0) {
            U[kk * 48 +  0 + j] = a0 + ldin(bd, 0, flag);
            U[kk * 48 + 16 + j] = a1 + ldin(bd, 1, flag);
            U[kk * 48 + 32 + j] = a2 + ldin(bd, 2, flag);
        }
    }
}

// ---------------------------------------------------------------------------
// k_main helpers, 512-thread / 32-pos version.
// zq pair layout: zH [32][40] shorts at 0, zL at +1280 shorts; pair = 2560.
// conv: thread = 1 d-channel (t&31) x 2 positions (((t>>5)&15)*2).
// Per-position FMA chain identical to v10 -> bit-identical z.
// ---------------------------------------------------------------------------
static __device__ __forceinline__ void conv_step(
        const float* __restrict__ patch, const float* __restrict__ cWe,
        const float* __restrict__ cbe, int dc, int t,
        unsigned short* __restrict__ zq,
        float* __restrict__ out_z, int b, int SP0) {
    const int cd = t & 31;
    const int ps = ((t >> 5) & 15) * 2;       // 16 groups x 2 positions
    const float4* wv = (const float4*)(cWe + (size_t)(dc + cd) * 48);
    const float bias = cbe[dc + cd];
    float za[2];
    #pragma unroll
    for (int p = 0; p < 2; ++p) za[p] = bias;
    #pragma unroll
    for (int q4 = 0; q4 < 12; ++q4) {
        float4 wq = wv[q4];
        #pragma unroll
        for (int p = 0; p < 2; ++p) {
            float4 v = ((const float4*)(patch + (ps + p) * 48))[q4];
            za[p] = fmaf(v.x, wq.x, za[p]);
            za[p] = fmaf(v.y, wq.y, za[p]);
            za[p] = fmaf(v.z, wq.z, za[p]);
            za[p] = fmaf(v.w, wq.w, za[p]);
        }
    }
    float zf[2];
    #pragma unroll
    for (int p = 0; p < 2; ++p) {
        float z = fmaxf(za[p], 0.f);
        unsigned short h = f2bf(z);
        unsigned short l = f2bf(z - bfu(h));
        zq[(ps + p) * 40 + cd] = h;
        zq[1280 + (ps + p) * 40 + cd] = l;
        zf[p] = bfu(h) + bfu(l);
    }
    size_t zbase = (size_t)(b * 512 + dc + cd) * 1024 + SP0 + ps;
    *(float2*)(out_z + zbase) = (float2){zf[0], zf[1]};
}

// Each wave handles code-tiles wave*4+j (j=0..3): acc[2 mt][4 j], 32 VGPRs.
static __device__ __forceinline__ void mfma_step(
        const unsigned short* __restrict__ zq,
        const unsigned short* __restrict__ cbHS,
        const unsigned short* __restrict__ cbLS,
        int dcPrev, int wave, int quad, int lcol, int flag, floatx4 (&acc)[2][4]) {
    const int lane = quad * 16 + lcol;
    short8 aH[2], aL[2];
    #pragma unroll
    for (int mt = 0; mt < 2; ++mt) {
        aH[mt] = *(const short8*)(zq + (mt * 16 + lcol) * 40 + quad * 8);
        aL[mt] = *(const short8*)(zq + 1280 + (mt * 16 + lcol) * 40 + quad * 8);
    }
    const unsigned short* fbH = cbHS + (size_t)dcPrev * 512 + (size_t)(wave * 4) * 512 + lane * 8;
    #pragma unroll
    for (int j = 0; j < 4; ++j) {
        short8 bH = *(const short8*)(fbH + j * 512);
        #pragma unroll
        for (int mt = 0; mt < 2; ++mt) {
            acc[mt][j] = __builtin_amdgcn_mfma_f32_16x16x32_bf16(aH[mt], bH, acc[mt][j], 0, 0, 0);
            acc[mt][j] = __builtin_amdgcn_mfma_f32_16x16x32_bf16(aL[mt], bH, acc[mt][j], 0, 0, 0);
        }
    }
    if (!flag) {   // fp32 inputs: third term zh*cbL
        const unsigned short* fbL = cbLS + (size_t)dcPrev * 512 + (size_t)(wave * 4) * 512 + lane * 8;
        #pragma unroll
        for (int j = 0; j < 4; ++j) {
            short8 bL = *(const short8*)(fbL + j * 512);
            #pragma unroll
            for (int mt = 0; mt < 2; ++mt)
                acc[mt][j] = __builtin_amdgcn_mfma_f32_16x16x32_bf16(aH[mt], bL, acc[mt][j], 0, 0, 0);
        }
    }
}

// best/second combine: (a1,ak,a2) <- merge (o1,ok,o2). Order-independent
// tournament (ties -> gap 0), so reshaping the reduction tree is safe.
static __device__ __forceinline__ void bmerge(float& a1, int& ak, float& a2,
                                              float o1, int ok, float o2) {
    if (o1 < a1)      { a2 = fminf(a1, o2); a1 = o1; ak = ok; }
    else if (o1 > a1) { a2 = fminf(a2, o1); }
    else              { a2 = a1; if (ok < ak) ak = ok; }
}

// ---------------------------------------------------------------------------
// FUSED main v11: 1024 blocks x 512 threads, 32-pos tiles -> 4 blocks/CU x
// 8 waves = 32 waves/CU (was 16). acc[2][4] = 32 VGPRs; LDS 16 KiB/block;
// __launch_bounds__(512,8) caps VGPR at 64 (r8 fit 64 with 2x the acc regs).
// Latency-coverage theory, second doubling. Arithmetic bit-identical.
// ---------------------------------------------------------------------------
__global__ __launch_bounds__(512, 8) void k_main(
        const void* __restrict__ x, const float* __restrict__ cWe,
        const float* __restrict__ cbe, const int* __restrict__ flagp,
        const unsigned short* __restrict__ cbHS, const unsigned short* __restrict__ cbLS,
        const float* __restrict__ cbT, const float* __restrict__ w2,
        float* __restrict__ out_z, float* __restrict__ out_e,
        int* __restrict__ idx, int* __restrict__ scnt, int* __restrict__ spos,
        int skipTail) {
    __shared__ __align__(16) char smc[16384];
    float* patch = (float*)smc;                               // [32][48] fp32
    unsigned short* zb = (unsigned short*)(smc + 6144);       // 2 pairs x 2560 shorts

    const int t = threadIdx.x;
    const int bid = blockIdx.x;
    const int q = ((bid & 7) << 7) | (bid >> 3);   // XCD co-location swizzle (1024)
    const int P0 = q * 32;
    const int b = P0 >> 10, SP0 = P0 & 1023;
    const int flag = *flagp;
    const int wave = t >> 6, lane = t & 63;
    const int quad = lane >> 4, lcol = lane & 15;

    // stage x patches once (32 pos x 48 vals)
    for (int e = t; e < 1536; e += 512) {
        int pid = e / 48, kk = e % 48;
        int c = kk >> 4, r = (kk >> 2) & 3, s = kk & 3;
        int pos = P0 + pid;
        int bb = pos >> 10, sp = pos & 1023, i = sp >> 5, j = sp & 31;
        patch[pid * 48 + kk] = ldin(x, ((bb * 3 + c) * 128 + (i * 4 + r)) * 128 + (j * 4 + s), flag);
    }

    floatx4 acc[2][4];
    #pragma unroll
    for (int mt = 0; mt < 2; ++mt)
        #pragma unroll
        for (int j = 0; j < 4; ++j) acc[mt][j] = (floatx4){0.f, 0.f, 0.f, 0.f};

    ldsbar();
    conv_step(patch, cWe, cbe, 0, t, zb, out_z, b, SP0);      // chunk 0 -> pair 0
    for (int dc = 32; dc < 512; dc += 32) {
        ldsbar();
        const int p = (dc >> 5) & 1;
        conv_step(patch, cWe, cbe, dc, t, zb + p * 2560, out_z, b, SP0);
        mfma_step(zb + (p ^ 1) * 2560, cbHS, cbLS, dc - 32, wave, quad, lcol, flag, acc);
    }
    ldsbar();
    mfma_step(zb + 2560, cbHS, cbLS, 480, wave, quad, lcol, flag, acc);

    // ---- epilogue: per-lane best/second over its 4 codes, then shuffle ----
    float s1[2][4], s2[2][4]; int k1[2][4];
    #pragma unroll
    for (int mt = 0; mt < 2; ++mt)
        #pragma unroll
        for (int r = 0; r < 4; ++r) { s1[mt][r] = 1e30f; s2[mt][r] = 1e30f; k1[mt][r] = 511; }
    #pragma unroll
    for (int j = 0; j < 4; ++j) {
        int code = (wave * 4 + j) * 16 + lcol;
        float wk = w2[code];
        #pragma unroll
        for (int mt = 0; mt < 2; ++mt)
            #pragma unroll
            for (int r = 0; r < 4; ++r) {
                float s = wk - 2.f * acc[mt][j][r];
                bmerge(s1[mt][r], k1[mt][r], s2[mt][r], s, code, 1e30f);
            }
    }
    // overlay reduction arrays on patch region (patch dead after last conv+bar)
    float* sS1 = (float*)smc;             // [32 pos][8 wave]
    int*   sK1 = (int*)(smc + 1024);
    float* sS2 = (float*)(smc + 2048);
    int*   ii  = (int*)(smc + 3072);      // [32]
    #pragma unroll
    for (int mt = 0; mt < 2; ++mt)
        #pragma unroll
        for (int r = 0; r < 4; ++r) {
            float a1 = s1[mt][r], a2 = s2[mt][r]; int ak = k1[mt][r];
            #pragma unroll
            for (int m = 1; m < 16; m <<= 1) {
                float o1 = __shfl_xor(a1, m);
                float o2 = __shfl_xor(a2, m);
                int   ok = __shfl_xor(ak, m);
                bmerge(a1, ak, a2, o1, ok, o2);
            }
            if (lcol == 0) {
                int pos = mt * 16 + quad * 4 + r;
                sS1[pos * 8 + wave] = a1;
                sK1[pos * 8 + wave] = ak;
                sS2[pos * 8 + wave] = a2;
            }
        }
    __syncthreads();
    if (t < 32) {
        float a1 = sS1[t * 8]; int ak = sK1[t * 8]; float a2 = sS2[t * 8];
        #pragma unroll
        for (int w = 1; w < 8; ++w)
            bmerge(a1, ak, a2, sS1[t * 8 + w], sK1[t * 8 + w], sS2[t * 8 + w]);
        ak &= 511;
        ii[t] = ak;
        unsigned int flagged = 0u;
        if (a2 - a1 < EPS_GAP) {
            int slot = atomicAdd(scnt, 1);
            if (slot < MAXSUS) { spos[slot] = P0 + t; flagged = 1u; }
        }
        idx[P0 + t] = (int)((unsigned)ak | (flagged << 31));
    }
    __syncthreads();

    // ---- fused emb: out_e[b][d][SP0+sp] = cbT[ii[sp]][d] ----
    const int sp = t & 31, dq = t >> 5;   // 16 groups x 32 d
    const float* row = cbT + (size_t)ii[sp] * 512;
    const size_t obase = ((size_t)b * 512) * 1024 + SP0 + sp;
    for (int d0 = dq * 32; d0 < dq * 32 + 32; d0 += 4) {
        if (skipTail && b == 31 && d0 >= 448) break;
        float4 v = *(const float4*)(row + d0);
        out_e[obase + (size_t)(d0    ) * 1024] = v.x;
        out_e[obase + (size_t)(d0 + 1) * 1024] = v.y;
        out_e[obase + (size_t)(d0 + 2) * 1024] = v.z;
        out_e[obase + (size_t)(d0 + 3) * 1024] = v.w;
    }
}

// ---------------------------------------------------------------------------
// FUSED post: recon (bid 0..127) ∥ rescore (bid 128..255) in one launch.
// ---------------------------------------------------------------------------
__global__ __launch_bounds__(256) void k_post(
        const float* __restrict__ out_z, const void* __restrict__ cb,
        const double* __restrict__ w2d, int* __restrict__ idx,
        const int* __restrict__ scnt, const int* __restrict__ spos,
        const float* __restrict__ U, const int* __restrict__ flagp,
        float* __restrict__ out_e, float* __restrict__ out_r, int skipTail) {
    __shared__ float zsh[512];
    __shared__ float rs[256];
    __shared__ int rk[256];
    __shared__ int bc[2];
    const int bid = blockIdx.x;
    const int t = threadIdx.x;

    if (bid < 128) {
        // ---- recon role ----
        const int pos = bid * 256 + t;
        const int v0 = idx[pos];
        if (v0 >= 0) {
            const int id = v0 & 511;
            const int b = pos >> 10, sp = pos & 1023, i = sp >> 5, j = sp & 31;
            const float* u = &U[(size_t)id * 48];
            #pragma unroll
            for (int c = 0; c < 3; ++c)
                #pragma unroll
                for (int uu = 0; uu < 4; ++uu) {
                    float4 q = *(const float4*)(&u[c * 16 + uu * 4]);
                    float4 o;
                    o.x = 1.f / (1.f + __expf(-q.x));
                    o.y = 1.f / (1.f + __expf(-q.y));
                    o.z = 1.f / (1.f + __expf(-q.z));
                    o.w = 1.f / (1.f + __expf(-q.w));
                    *(float4*)(&out_r[((size_t)((b * 3 + c) * 128) + (i * 4 + uu)) * 128 + j * 4]) = o;
                }
        }
        return;
    }

    // ---- rescore role ----
    const int flag = *flagp;
    int n = *scnt; if (n > MAXSUS) n = MAXSUS;
    for (int s = bid - 128; s < n; s += 128) {
        int p = spos[s] & 32767;
        int b = p >> 10, sp = p & 1023;
        __syncthreads();
        zsh[t]       = out_z[(size_t)(b * 512 + t) * 1024 + sp];
        zsh[t + 256] = out_z[(size_t)(b * 512 + t + 256) * 1024 + sp];
        __syncthreads();
        float bs = 1e30f; int bk = 511;
        for (int cc = 0; cc < 2; ++cc) {
            int k = t + cc * 256;
            double a = 0.0;
            for (int d = 0; d < 512; ++d)
                a = fma((double)zsh[d], (double)ldin(cb, (size_t)d * 512 + k, flag), a);
            float sc = (float)(w2d[k] - 2.0 * a);
            if (sc < bs || (sc == bs && k < bk)) { bs = sc; bk = k; }
        }
        rs[t] = bs; rk[t] = bk;
        __syncthreads();
        for (int str = 128; str > 0; str >>= 1) {
            if (t < str) {
                float so = rs[t + str]; int ko = rk[t + str];
                if (so < rs[t] || (so == rs[t] && ko < rk[t])) { rs[t] = so; rk[t] = ko; }
            }
            __syncthreads();
        }
        if (t == 0) {
            int kstar = rk[0] & 511;
            int old = idx[p] & 511;
            bc[0] = kstar; bc[1] = (kstar != old);
            idx[p] = kstar;                       // clears suspect flag too
        }
        __syncthreads();
        const int kk = bc[0];
        if (bc[1]) {
            for (int d = t; d < 512; d += 256) {
                if (skipTail && b == 31 && d >= 448) continue;
                out_e[(size_t)(b * 512 + d) * 1024 + sp] = ldin(cb, (size_t)d * 512 + kk, flag);
            }
        }
        // recon for this suspect (recon role skipped it) — always write
        if (t < 48) {
            float q = U[(size_t)kk * 48 + t];
            float o = 1.f / (1.f + __expf(-q));
            int c = t >> 4, uu = (t >> 2) & 3, vv = t & 3;
            int i = sp >> 5, j = sp & 31;
            out_r[((size_t)((b * 3 + c) * 128) + (i * 4 + uu)) * 128 + j * 4 + vv] = o;
        }
    }
}

// ---------------------------------------------------------------------------
__global__ __launch_bounds__(1024) void k_fixup(
        const void* __restrict__ cb, const int* __restrict__ flagp,
        const int* __restrict__ idx, float* __restrict__ out_e) {
    __shared__ int ii[1024];
    __shared__ int sflag;
    const int t = threadIdx.x;
    if (t == 0) sflag = *flagp;
    ii[t] = idx[31744 + t] & 511;
    __syncthreads();
    const int flag = sflag;
    for (int e = t; e < 65536; e += 1024) {
        int d = 448 + (e >> 10), sp = e & 1023;
        out_e[((size_t)(31 * 512 + d)) * 1024 + sp] = ldin(cb, (size_t)d * 512 + ii[sp], flag);
    }
}

// ---------------------------------------------------------------------------
extern "C" void kernel_launch(void* const* d_in, const int* in_sizes, int n_in,
                              void* d_out, int out_size, void* d_ws, size_t ws_size,
                              hipStream_t stream) {
    const void* x  = d_in[0];
    const void* We = d_in[1];
    const void* be = d_in[2];
    const void* Wd = d_in[3];
    const void* bd = d_in[4];
    const void* cb = d_in[5];

    float* out   = (float*)d_out;
    float* out_r = out;                       // 1,572,864 fp32 (6.29 MB)
    float* out_z = out + 1572864;             // 16,777,216 fp32
    float* out_e = out + 18350080;            // 16,777,216 fp32

    // Read-mostly tables in out_r (recon overwrites during k_post; nothing in
    // k_post reads them — rescore uses raw cb):
    char* Rb = (char*)out_r;
    float* cbT          = (float*)(Rb);                    // 1,048,576 B
    float* cWe          = (float*)(Rb + 1048576);          //    98,304 B
    float* cbe          = (float*)(Rb + 1146880);          //     2,048 B
    float* cWd          = (float*)(Rb + 1148928);          //    98,304 B
    float* cbd          = (float*)(Rb + 1247232);          //        64 B
    unsigned short* cbHS= (unsigned short*)(Rb + 1247296); //   524,288 B (swizzled)
    unsigned short* cbLS= (unsigned short*)(Rb + 1771584); //   524,288 B (swizzled)

    // Tail scratch: prefer d_ws; else last 256 KB of out_e (fixup required).
    int tailWS = (ws_size >= 262144) ? 1 : 0;
    char* Tbase = tailWS ? (char*)d_ws : ((char*)out_e + 66846720);
    int skipTail = tailWS ? 0 : 1;
    int*    idx  = (int*)   (Tbase);            // 131,072 B
    float*  U    = (float*) (Tbase + 131072);   //  98,304 B
    float*  w2   = (float*) (Tbase + 229376);   //   2,048 B
    double* w2d  = (double*)(Tbase + 231424);   //   4,096 B
    int*    flag = (int*)   (Tbase + 235520);   //      64 B
    int*    scnt = (int*)   (Tbase + 235584);   //      64 B
    int*    spos = (int*)   (Tbase + 235648);   //  16,384 B

    k_sniff<<<1, 1024, 0, stream>>>(cb, flag, scnt);
    k_prepAll<<<395, 256, 0, stream>>>(We, be, Wd, bd, cb, flag,
                                       cWe, cbe, cWd, cbd,
                                       cbT, cbHS, cbLS, w2, w2d, U);
    k_main<<<1024, 512, 0, stream>>>(x, cWe, cbe, flag, cbHS, cbLS, cbT, w2,
                                     out_z, out_e, idx, scnt, spos, skipTail);
    k_post<<<256, 256, 0, stream>>>(out_z, cb, w2d, idx, scnt, spos, U, flag,
                                    out_e, out_r, skipTail);
    if (skipTail)
        k_fixup<<<1, 1024, 0, stream>>>(cb, flag, idx, out_e);
}

// Round 10
// 398.508 us; speedup vs baseline: 1.0098x; 1.0098x over previous
//
#include <hip/hip_runtime.h>
#include <hip/hip_bf16.h>

// B=32, C=3, H=W=128, D=512, K=512, S=4, NPOS=32768
#define NPOS 32768
#define EPS_GAP 4e-3f
#define MAXSUS 4096

typedef __attribute__((ext_vector_type(8))) short short8;
typedef __attribute__((ext_vector_type(4))) float floatx4;

static __device__ __forceinline__ float bfu(unsigned short h) {
    return __uint_as_float(((unsigned int)h) << 16);
}
static __device__ __forceinline__ unsigned short f2bf(float f) {
    unsigned int u = __float_as_uint(f);
    u = (u + 0x7fffu + ((u >> 16) & 1u)) >> 16;   // RNE
    return (unsigned short)u;
}
static __device__ __forceinline__ float ldin(const void* p, size_t i, int flag) {
    return flag ? bfu(((const unsigned short*)p)[i]) : ((const float*)p)[i];
}

// LDS-only barrier: drains ds ops (lgkmcnt) but leaves global loads/stores
// in flight across the barrier (no vmcnt(0) drain).
static __device__ __forceinline__ void ldsbar() {
    asm volatile("s_waitcnt lgkmcnt(0)" ::: "memory");
    __builtin_amdgcn_s_barrier();
    asm volatile("" ::: "memory");
}

// Swizzled B-fragment offset (units: shorts). Element (code k, dim d) lands at
// the position the MFMA lane-load wants: fragment(chunk=d>>5, codeTile=k>>4)
// is 64 lanes x 8 shorts contiguous; lane = ((d>>3)&3)*16 + (k&15), sub = d&7.
static __device__ __forceinline__ size_t swzoff(int k, int d) {
    return (size_t)(d >> 5) * 16384 + (size_t)(k >> 4) * 512
         + (size_t)((((d >> 3) & 3) * 16 + (k & 15)) * 8) + (d & 7);
}

// ---------------------------------------------------------------------------
// Sniff: decide bf16 vs fp32 input encoding from codebook column norms.
// ---------------------------------------------------------------------------
__global__ __launch_bounds__(1024) void k_sniff(const void* __restrict__ cb,
                                                int* __restrict__ flag,
                                                int* __restrict__ scnt) {
    __shared__ float s[1024];
    const int t = threadIdx.x;
    const int k = t & 63, g = t >> 6;          // 16 groups x 32 d
    const unsigned short* u = (const unsigned short*)cb;
    float acc = 0.f;
    for (int d = g * 32; d < g * 32 + 32; ++d) {
        float v = bfu(u[(size_t)d * 512 + k]);
        acc = fmaf(v, v, acc);
    }
    s[t] = acc;
    __syncthreads();
    if (t < 64) {
        float a = 0.f;
        #pragma unroll
        for (int g2 = 0; g2 < 16; ++g2) a += s[g2 * 64 + k];
        int ok = (a >= 100.f && a <= 2000.f) ? 1 : 0;
        unsigned long long m = __ballot(ok);
        if (k == 0) {
            *flag = (m == ~0ull) ? 1 : 0;
            *scnt = 0;
        }
    }
}

// ---------------------------------------------------------------------------
// FUSED prep: one launch, role-split by blockIdx. NO cross-role dependencies.
// ---------------------------------------------------------------------------
__global__ __launch_bounds__(256) void k_prepAll(
        const void* __restrict__ We, const void* __restrict__ be,
        const void* __restrict__ Wd, const void* __restrict__ bd,
        const void* __restrict__ cb, const int* __restrict__ flagp,
        float* __restrict__ cWe, float* __restrict__ cbe,
        float* __restrict__ cWd, float* __restrict__ cbd,
        float* __restrict__ cbT, unsigned short* __restrict__ cbHS,
        unsigned short* __restrict__ cbLS,
        float* __restrict__ w2, double* __restrict__ w2d,
        float* __restrict__ U) {
    __shared__ float tile[64][65];
    __shared__ double sd[256];
    const int bid = blockIdx.x;
    const int t = threadIdx.x;
    const int flag = *flagp;

    if (bid < 195) {
        // ---- canonW ----
        int e = bid * 256 + t;
        if (e < 24576)       cWe[e]         = ldin(We, e, flag);
        else if (e < 25088)  cbe[e - 24576] = ldin(be, e - 24576, flag);
        else if (e < 49664)  cWd[e - 25088] = ldin(Wd, e - 25088, flag);
        else if (e < 49667)  cbd[e - 49664] = ldin(bd, e - 49664, flag);
    } else if (bid < 259) {
        // ---- prepcb ----
        const int bb = bid - 195;
        const int D0 = (bb >> 3) * 64, K0 = (bb & 7) * 64;
        for (int it = 0; it < 16; ++it) {
            int r = (t >> 6) + 4 * it, c = t & 63;
            tile[r][c] = ldin(cb, (size_t)(D0 + r) * 512 + K0 + c, flag);
        }
        __syncthreads();
        for (int it = 0; it < 16; ++it) {
            int r = (t >> 6) + 4 * it, c = t & 63;
            float v = tile[c][r];
            int k = K0 + r, d = D0 + c;
            cbT[(size_t)k * 512 + d] = v;
            size_t o2 = swzoff(k, d);
            unsigned short h = f2bf(v);
            cbHS[o2] = h;
            cbLS[o2] = f2bf(v - bfu(h));
        }
    } else if (bid < 267) {
        // ---- w2 ----
        const int k = (bid - 259) * 64 + (t & 63);
        const int g = t >> 6;                  // 4 groups x 128 d
        double acc = 0.0;
        for (int d = g * 128; d < g * 128 + 128; ++d) {
            double v = (double)ldin(cb, (size_t)d * 512 + k, flag);
            acc += v * v;
        }
        sd[t] = acc;
        __syncthreads();
        if (t < 64) {
            double a = sd[t] + sd[t + 64] + sd[t + 128] + sd[t + 192];
            w2[k] = (float)a;
            w2d[k] = a;
        }
    } else {
        // ---- udec: U[k][c*16+u*4+v] = sum_d cb[d][k]*Wd[c][d][3-u][3-v]+bd[c]
        const int kk = (bid - 267) * 4 + (t >> 6);
        const int lane = t & 63;
        const int j = lane >> 2, dpart = lane & 3;
        const int u = (j >> 2) & 3, v = j & 3;
        int woff[3];
        #pragma unroll
        for (int m = 0; m < 3; ++m) woff[m] = m * 8192 + (3 - u) * 4 + (3 - v);
        float a0 = 0.f, a1 = 0.f, a2 = 0.f;
        for (int i = 0; i < 128; ++i) {
            int d = dpart * 128 + i;
            float cw = ldin(cb, (size_t)d * 512 + kk, flag);
            a0 = fmaf(cw, ldin(Wd, (size_t)(woff[0] + d * 16), flag), a0);
            a1 = fmaf(cw, ldin(Wd, (size_t)(woff[1] + d * 16), flag), a1);
            a2 = fmaf(cw, ldin(Wd, (size_t)(woff[2] + d * 16), flag), a2);
        }
        a0 += __shfl_xor(a0, 1); a0 += __shfl_xor(a0, 2);
        a1 += __shfl_xor(a1, 1); a1 += __shfl_xor(a1, 2);
        a2 += __shfl_xor(a2, 1); a2 += __shfl_xor(a2, 2);
        if (dpart == 0) {
            U[kk * 48 +  0 + j] = a0 + ldin(bd, 0, flag);
            U[kk * 48 + 16 + j] = a1 + ldin(bd, 1, flag);
            U[kk * 48 + 32 + j] = a2 + ldin(bd, 2, flag);
        }
    }
}

// ---------------------------------------------------------------------------
// k_main helpers (r8 structure; patch row stride = 52 floats, 16B-aligned).
// zq pair layout: zH [64][40] shorts at 0, zL at +2560; pair = 5120 shorts.
// conv v12: thread = 2 d-channels x 2 positions -- each patch float4 read
// feeds BOTH channels (24 ds_read_b128/thread/chunk vs r8's 48). Per-(pos,d)
// FMA chain identical to r8 -> bit-identical z.
// ---------------------------------------------------------------------------
static __device__ __forceinline__ void conv_step(
        const float* __restrict__ patch, const float* __restrict__ cWe,
        const float* __restrict__ cbe, int dc, int t,
        unsigned short* __restrict__ zq,
        float* __restrict__ out_z, int b, int SP0) {
    const int cd0 = (t & 15) * 2;             // channel pair: cd0, cd0+1
    const int ps = (t >> 4) * 2;              // 32 groups x 2 positions
    const float4* wv0 = (const float4*)(cWe + (size_t)(dc + cd0) * 48);
    const float4* wv1 = (const float4*)(cWe + (size_t)(dc + cd0 + 1) * 48);
    const float b0 = cbe[dc + cd0], b1 = cbe[dc + cd0 + 1];
    float za[2][2];                           // [pos][chan]
    za[0][0] = b0; za[1][0] = b0;
    za[0][1] = b1; za[1][1] = b1;
    #pragma unroll
    for (int q4 = 0; q4 < 12; ++q4) {
        float4 w0 = wv0[q4];
        float4 w1 = wv1[q4];
        #pragma unroll
        for (int p = 0; p < 2; ++p) {
            float4 v = ((const float4*)(patch + (ps + p) * 52))[q4];
            za[p][0] = fmaf(v.x, w0.x, za[p][0]);
            za[p][0] = fmaf(v.y, w0.y, za[p][0]);
            za[p][0] = fmaf(v.z, w0.z, za[p][0]);
            za[p][0] = fmaf(v.w, w0.w, za[p][0]);
            za[p][1] = fmaf(v.x, w1.x, za[p][1]);
            za[p][1] = fmaf(v.y, w1.y, za[p][1]);
            za[p][1] = fmaf(v.z, w1.z, za[p][1]);
            za[p][1] = fmaf(v.w, w1.w, za[p][1]);
        }
    }
    float zf[2][2];                           // [chan][pos]
    #pragma unroll
    for (int p = 0; p < 2; ++p)
        #pragma unroll
        for (int c = 0; c < 2; ++c) {
            float z = fmaxf(za[p][c], 0.f);
            unsigned short h = f2bf(z);
            unsigned short l = f2bf(z - bfu(h));
            zq[(ps + p) * 40 + cd0 + c] = h;
            zq[2560 + (ps + p) * 40 + cd0 + c] = l;
            zf[c][p] = bfu(h) + bfu(l);
        }
    size_t zbase = (size_t)(b * 512 + dc + cd0) * 1024 + SP0 + ps;
    *(float2*)(out_z + zbase)        = (float2){zf[0][0], zf[0][1]};
    *(float2*)(out_z + zbase + 1024) = (float2){zf[1][0], zf[1][1]};
}

// Each wave handles code-tiles wave*4+j (j=0..3): acc[4 mt][4 j].
static __device__ __forceinline__ void mfma_step(
        const unsigned short* __restrict__ zq,
        const unsigned short* __restrict__ cbHS,
        const unsigned short* __restrict__ cbLS,
        int dcPrev, int wave, int quad, int lcol, int flag, floatx4 (&acc)[4][4]) {
    const int lane = quad * 16 + lcol;
    short8 aH[4], aL[4];
    #pragma unroll
    for (int mt = 0; mt < 4; ++mt) {
        aH[mt] = *(const short8*)(zq + (mt * 16 + lcol) * 40 + quad * 8);
        aL[mt] = *(const short8*)(zq + 2560 + (mt * 16 + lcol) * 40 + quad * 8);
    }
    const unsigned short* fbH = cbHS + (size_t)dcPrev * 512 + (size_t)(wave * 4) * 512 + lane * 8;
    #pragma unroll
    for (int j = 0; j < 4; ++j) {
        short8 bH = *(const short8*)(fbH + j * 512);
        #pragma unroll
        for (int mt = 0; mt < 4; ++mt) {
            acc[mt][j] = __builtin_amdgcn_mfma_f32_16x16x32_bf16(aH[mt], bH, acc[mt][j], 0, 0, 0);
            acc[mt][j] = __builtin_amdgcn_mfma_f32_16x16x32_bf16(aL[mt], bH, acc[mt][j], 0, 0, 0);
        }
    }
    if (!flag) {   // fp32 inputs: third term zh*cbL
        const unsigned short* fbL = cbLS + (size_t)dcPrev * 512 + (size_t)(wave * 4) * 512 + lane * 8;
        #pragma unroll
        for (int j = 0; j < 4; ++j) {
            short8 bL = *(const short8*)(fbL + j * 512);
            #pragma unroll
            for (int mt = 0; mt < 4; ++mt)
                acc[mt][j] = __builtin_amdgcn_mfma_f32_16x16x32_bf16(aH[mt], bL, acc[mt][j], 0, 0, 0);
        }
    }
}

// best/second combine: (a1,ak,a2) <- merge (o1,ok,o2). Order-independent
// tournament (ties -> gap 0), so reshaping the reduction tree is safe.
static __device__ __forceinline__ void bmerge(float& a1, int& ak, float& a2,
                                              float o1, int ok, float o2) {
    if (o1 < a1)      { a2 = fminf(a1, o2); a1 = o1; ak = ok; }
    else if (o1 > a1) { a2 = fminf(a2, o1); }
    else              { a2 = a1; if (ok < ak) ak = ok; }
}

// ---------------------------------------------------------------------------
// FUSED main v12 = r8 (512 blocks x 512 threads, 64-pos, 16 waves/CU — the
// proven 123us config) + conv 2cd x 2pos mapping (patch ds_reads halved) +
// patch stride 52 (aligned, conflict-free). r9's 32-wave config REVERTED:
// it amplified HBM traffic 3.4x (FETCH 70MB, WRITE 400MB).
// ---------------------------------------------------------------------------
__global__ __launch_bounds__(512, 4) void k_main(
        const void* __restrict__ x, const float* __restrict__ cWe,
        const float* __restrict__ cbe, const int* __restrict__ flagp,
        const unsigned short* __restrict__ cbHS, const unsigned short* __restrict__ cbLS,
        const float* __restrict__ cbT, const float* __restrict__ w2,
        float* __restrict__ out_z, float* __restrict__ out_e,
        int* __restrict__ idx, int* __restrict__ scnt, int* __restrict__ spos,
        int skipTail) {
    __shared__ __align__(16) char smc[33792];
    float* patch = (float*)smc;                               // [64][52] fp32
    unsigned short* zb = (unsigned short*)(smc + 13312);      // 2 pairs x 5120 shorts

    const int t = threadIdx.x;
    const int bid = blockIdx.x;
    const int q = ((bid & 7) << 6) | (bid >> 3);   // XCD co-location swizzle
    const int P0 = q * 64;
    const int b = P0 >> 10, SP0 = P0 & 1023;
    const int flag = *flagp;
    const int wave = t >> 6, lane = t & 63;
    const int quad = lane >> 4, lcol = lane & 15;

    // stage x patches once (64 pos x 48 vals, padded rows of 52)
    for (int e = t; e < 3072; e += 512) {
        int pid = e / 48, kk = e % 48;
        int c = kk >> 4, r = (kk >> 2) & 3, s = kk & 3;
        int pos = P0 + pid;
        int bb = pos >> 10, sp = pos & 1023, i = sp >> 5, j = sp & 31;
        patch[pid * 52 + kk] = ldin(x, ((bb * 3 + c) * 128 + (i * 4 + r)) * 128 + (j * 4 + s), flag);
    }

    floatx4 acc[4][4];
    #pragma unroll
    for (int mt = 0; mt < 4; ++mt)
        #pragma unroll
        for (int j = 0; j < 4; ++j) acc[mt][j] = (floatx4){0.f, 0.f, 0.f, 0.f};

    ldsbar();
    conv_step(patch, cWe, cbe, 0, t, zb, out_z, b, SP0);      // chunk 0 -> pair 0
    for (int dc = 32; dc < 512; dc += 32) {
        ldsbar();
        const int p = (dc >> 5) & 1;
        conv_step(patch, cWe, cbe, dc, t, zb + p * 5120, out_z, b, SP0);
        mfma_step(zb + (p ^ 1) * 5120, cbHS, cbLS, dc - 32, wave, quad, lcol, flag, acc);
    }
    ldsbar();
    mfma_step(zb + 5120, cbHS, cbLS, 480, wave, quad, lcol, flag, acc);

    // ---- epilogue: per-lane best/second over its 4 codes, then shuffle ----
    float s1[4][4], s2[4][4]; int k1[4][4];
    #pragma unroll
    for (int mt = 0; mt < 4; ++mt)
        #pragma unroll
        for (int r = 0; r < 4; ++r) { s1[mt][r] = 1e30f; s2[mt][r] = 1e30f; k1[mt][r] = 511; }
    #pragma unroll
    for (int j = 0; j < 4; ++j) {
        int code = (wave * 4 + j) * 16 + lcol;
        float wk = w2[code];
        #pragma unroll
        for (int mt = 0; mt < 4; ++mt)
            #pragma unroll
            for (int r = 0; r < 4; ++r) {
                float s = wk - 2.f * acc[mt][j][r];
                bmerge(s1[mt][r], k1[mt][r], s2[mt][r], s, code, 1e30f);
            }
    }
    // overlay reduction arrays on patch region (patch dead after last conv+bar)
    float* sS1 = (float*)smc;             // [64 pos][8 wave]
    int*   sK1 = (int*)(smc + 2048);
    float* sS2 = (float*)(smc + 4096);
    int*   ii  = (int*)(smc + 6144);      // [64]
    #pragma unroll
    for (int mt = 0; mt < 4; ++mt)
        #pragma unroll
        for (int r = 0; r < 4; ++r) {
            float a1 = s1[mt][r], a2 = s2[mt][r]; int ak = k1[mt][r];
            #pragma unroll
            for (int m = 1; m < 16; m <<= 1) {
                float o1 = __shfl_xor(a1, m);
                float o2 = __shfl_xor(a2, m);
                int   ok = __shfl_xor(ak, m);
                bmerge(a1, ak, a2, o1, ok, o2);
            }
            if (lcol == 0) {
                int pos = mt * 16 + quad * 4 + r;
                sS1[pos * 8 + wave] = a1;
                sK1[pos * 8 + wave] = ak;
                sS2[pos * 8 + wave] = a2;
            }
        }
    __syncthreads();
    if (t < 64) {
        float a1 = sS1[t * 8]; int ak = sK1[t * 8]; float a2 = sS2[t * 8];
        #pragma unroll
        for (int w = 1; w < 8; ++w)
            bmerge(a1, ak, a2, sS1[t * 8 + w], sK1[t * 8 + w], sS2[t * 8 + w]);
        ak &= 511;
        ii[t] = ak;
        unsigned int flagged = 0u;
        if (a2 - a1 < EPS_GAP) {
            int slot = atomicAdd(scnt, 1);
            if (slot < MAXSUS) { spos[slot] = P0 + t; flagged = 1u; }
        }
        idx[P0 + t] = (int)((unsigned)ak | (flagged << 31));
    }
    __syncthreads();

    // ---- fused emb: out_e[b][d][SP0+sp] = cbT[ii[sp]][d] ----
    const int sp = t & 63, dq = t >> 6;   // 8 groups x 64 d
    const float* row = cbT + (size_t)ii[sp] * 512;
    const size_t obase = ((size_t)b * 512) * 1024 + SP0 + sp;
    for (int d0 = dq * 64; d0 < dq * 64 + 64; d0 += 4) {
        if (skipTail && b == 31 && d0 >= 448) break;
        float4 v = *(const float4*)(row + d0);
        out_e[obase + (size_t)(d0    ) * 1024] = v.x;
        out_e[obase + (size_t)(d0 + 1) * 1024] = v.y;
        out_e[obase + (size_t)(d0 + 2) * 1024] = v.z;
        out_e[obase + (size_t)(d0 + 3) * 1024] = v.w;
    }
}

// ---------------------------------------------------------------------------
// FUSED post: recon (bid 0..127) ∥ rescore (bid 128..255) in one launch.
// ---------------------------------------------------------------------------
__global__ __launch_bounds__(256) void k_post(
        const float* __restrict__ out_z, const void* __restrict__ cb,
        const double* __restrict__ w2d, int* __restrict__ idx,
        const int* __restrict__ scnt, const int* __restrict__ spos,
        const float* __restrict__ U, const int* __restrict__ flagp,
        float* __restrict__ out_e, float* __restrict__ out_r, int skipTail) {
    __shared__ float zsh[512];
    __shared__ float rs[256];
    __shared__ int rk[256];
    __shared__ int bc[2];
    const int bid = blockIdx.x;
    const int t = threadIdx.x;

    if (bid < 128) {
        // ---- recon role ----
        const int pos = bid * 256 + t;
        const int v0 = idx[pos];
        if (v0 >= 0) {
            const int id = v0 & 511;
            const int b = pos >> 10, sp = pos & 1023, i = sp >> 5, j = sp & 31;
            const float* u = &U[(size_t)id * 48];
            #pragma unroll
            for (int c = 0; c < 3; ++c)
                #pragma unroll
                for (int uu = 0; uu < 4; ++uu) {
                    float4 q = *(const float4*)(&u[c * 16 + uu * 4]);
                    float4 o;
                    o.x = 1.f / (1.f + __expf(-q.x));
                    o.y = 1.f / (1.f + __expf(-q.y));
                    o.z = 1.f / (1.f + __expf(-q.z));
                    o.w = 1.f / (1.f + __expf(-q.w));
                    *(float4*)(&out_r[((size_t)((b * 3 + c) * 128) + (i * 4 + uu)) * 128 + j * 4]) = o;
                }
        }
        return;
    }

    // ---- rescore role ----
    const int flag = *flagp;
    int n = *scnt; if (n > MAXSUS) n = MAXSUS;
    for (int s = bid - 128; s < n; s += 128) {
        int p = spos[s] & 32767;
        int b = p >> 10, sp = p & 1023;
        __syncthreads();
        zsh[t]       = out_z[(size_t)(b * 512 + t) * 1024 + sp];
        zsh[t + 256] = out_z[(size_t)(b * 512 + t + 256) * 1024 + sp];
        __syncthreads();
        float bs = 1e30f; int bk = 511;
        for (int cc = 0; cc < 2; ++cc) {
            int k = t + cc * 256;
            double a = 0.0;
            for (int d = 0; d < 512; ++d)
                a = fma((double)zsh[d], (double)ldin(cb, (size_t)d * 512 + k, flag), a);
            float sc = (float)(w2d[k] - 2.0 * a);
            if (sc < bs || (sc == bs && k < bk)) { bs = sc; bk = k; }
        }
        rs[t] = bs; rk[t] = bk;
        __syncthreads();
        for (int str = 128; str > 0; str >>= 1) {
            if (t < str) {
                float so = rs[t + str]; int ko = rk[t + str];
                if (so < rs[t] || (so == rs[t] && ko < rk[t])) { rs[t] = so; rk[t] = ko; }
            }
            __syncthreads();
        }
        if (t == 0) {
            int kstar = rk[0] & 511;
            int old = idx[p] & 511;
            bc[0] = kstar; bc[1] = (kstar != old);
            idx[p] = kstar;                       // clears suspect flag too
        }
        __syncthreads();
        const int kk = bc[0];
        if (bc[1]) {
            for (int d = t; d < 512; d += 256) {
                if (skipTail && b == 31 && d >= 448) continue;
                out_e[(size_t)(b * 512 + d) * 1024 + sp] = ldin(cb, (size_t)d * 512 + kk, flag);
            }
        }
        // recon for this suspect (recon role skipped it) — always write
        if (t < 48) {
            float q = U[(size_t)kk * 48 + t];
            float o = 1.f / (1.f + __expf(-q));
            int c = t >> 4, uu = (t >> 2) & 3, vv = t & 3;
            int i = sp >> 5, j = sp & 31;
            out_r[((size_t)((b * 3 + c) * 128) + (i * 4 + uu)) * 128 + j * 4 + vv] = o;
        }
    }
}

// ---------------------------------------------------------------------------
__global__ __launch_bounds__(1024) void k_fixup(
        const void* __restrict__ cb, const int* __restrict__ flagp,
        const int* __restrict__ idx, float* __restrict__ out_e) {
    __shared__ int ii[1024];
    __shared__ int sflag;
    const int t = threadIdx.x;
    if (t == 0) sflag = *flagp;
    ii[t] = idx[31744 + t] & 511;
    __syncthreads();
    const int flag = sflag;
    for (int e = t; e < 65536; e += 1024) {
        int d = 448 + (e >> 10), sp = e & 1023;
        out_e[((size_t)(31 * 512 + d)) * 1024 + sp] = ldin(cb, (size_t)d * 512 + ii[sp], flag);
    }
}

// ---------------------------------------------------------------------------
extern "C" void kernel_launch(void* const* d_in, const int* in_sizes, int n_in,
                              void* d_out, int out_size, void* d_ws, size_t ws_size,
                              hipStream_t stream) {
    const void* x  = d_in[0];
    const void* We = d_in[1];
    const void* be = d_in[2];
    const void* Wd = d_in[3];
    const void* bd = d_in[4];
    const void* cb = d_in[5];

    float* out   = (float*)d_out;
    float* out_r = out;                       // 1,572,864 fp32 (6.29 MB)
    float* out_z = out + 1572864;             // 16,777,216 fp32
    float* out_e = out + 18350080;            // 16,777,216 fp32

    // Read-mostly tables in out_r (recon overwrites during k_post; nothing in
    // k_post reads them — rescore uses raw cb):
    char* Rb = (char*)out_r;
    float* cbT          = (float*)(Rb);                    // 1,048,576 B
    float* cWe          = (float*)(Rb + 1048576);          //    98,304 B
    float* cbe          = (float*)(Rb + 1146880);          //     2,048 B
    float* cWd          = (float*)(Rb + 1148928);          //    98,304 B
    float* cbd          = (float*)(Rb + 1247232);          //        64 B
    unsigned short* cbHS= (unsigned short*)(Rb + 1247296); //   524,288 B (swizzled)
    unsigned short* cbLS= (unsigned short*)(Rb + 1771584); //   524,288 B (swizzled)

    // Tail scratch: prefer d_ws; else last 256 KB of out_e (fixup required).
    int tailWS = (ws_size >= 262144) ? 1 : 0;
    char* Tbase = tailWS ? (char*)d_ws : ((char*)out_e + 66846720);
    int skipTail = tailWS ? 0 : 1;
    int*    idx  = (int*)   (Tbase);            // 131,072 B
    float*  U    = (float*) (Tbase + 131072);   //  98,304 B
    float*  w2   = (float*) (Tbase + 229376);   //   2,048 B
    double* w2d  = (double*)(Tbase + 231424);   //   4,096 B
    int*    flag = (int*)   (Tbase + 235520);   //      64 B
    int*    scnt = (int*)   (Tbase + 235584);   //      64 B
    int*    spos = (int*)   (Tbase + 235648);   //  16,384 B

    k_sniff<<<1, 1024, 0, stream>>>(cb, flag, scnt);
    k_prepAll<<<395, 256, 0, stream>>>(We, be, Wd, bd, cb, flag,
                                       cWe, cbe, cWd, cbd,
                                       cbT, cbHS, cbLS, w2, w2d, U);
    k_main<<<512, 512, 0, stream>>>(x, cWe, cbe, flag, cbHS, cbLS, cbT, w2,
                                    out_z, out_e, idx, scnt, spos, skipTail);
    k_post<<<256, 256, 0, stream>>>(out_z, cb, w2d, idx, scnt, spos, U, flag,
                                    out_e, out_r, skipTail);
    if (skipTail)
        k_fixup<<<1, 1024, 0, stream>>>(cb, flag, idx, out_e);
}

// Round 11
// 279.172 us; speedup vs baseline: 1.4415x; 1.4275x over previous
//
#include <hip/hip_runtime.h>
#include <hip/hip_bf16.h>

// B=32, C=3, H=W=128, D=512, K=512, S=4, NPOS=32768
#define NPOS 32768
#define EPS_GAP 4e-3f
#define MAXSUS 4096

typedef __attribute__((ext_vector_type(8))) short short8;
typedef __attribute__((ext_vector_type(4))) float floatx4;

static __device__ __forceinline__ float bfu(unsigned short h) {
    return __uint_as_float(((unsigned int)h) << 16);
}
static __device__ __forceinline__ unsigned short f2bf(float f) {
    unsigned int u = __float_as_uint(f);
    u = (u + 0x7fffu + ((u >> 16) & 1u)) >> 16;   // RNE
    return (unsigned short)u;
}
static __device__ __forceinline__ float ldin(const void* p, size_t i, int flag) {
    return flag ? bfu(((const unsigned short*)p)[i]) : ((const float*)p)[i];
}

// LDS-only barrier: drains ds ops (lgkmcnt) but leaves global loads/stores
// in flight across the barrier (no vmcnt(0) drain).
static __device__ __forceinline__ void ldsbar() {
    asm volatile("s_waitcnt lgkmcnt(0)" ::: "memory");
    __builtin_amdgcn_s_barrier();
    asm volatile("" ::: "memory");
}

// Swizzled B-fragment offset (units: shorts). Element (code k, dim d) lands at
// the position the MFMA lane-load wants: fragment(chunk=d>>5, codeTile=k>>4)
// is 64 lanes x 8 shorts contiguous; lane = ((d>>3)&3)*16 + (k&15), sub = d&7.
static __device__ __forceinline__ size_t swzoff(int k, int d) {
    return (size_t)(d >> 5) * 16384 + (size_t)(k >> 4) * 512
         + (size_t)((((d >> 3) & 3) * 16 + (k & 15)) * 8) + (d & 7);
}

// ---------------------------------------------------------------------------
// Sniff: decide bf16 vs fp32 input encoding from codebook column norms.
// ---------------------------------------------------------------------------
__global__ __launch_bounds__(1024) void k_sniff(const void* __restrict__ cb,
                                                int* __restrict__ flag,
                                                int* __restrict__ scnt) {
    __shared__ float s[1024];
    const int t = threadIdx.x;
    const int k = t & 63, g = t >> 6;          // 16 groups x 32 d
    const unsigned short* u = (const unsigned short*)cb;
    float acc = 0.f;
    for (int d = g * 32; d < g * 32 + 32; ++d) {
        float v = bfu(u[(size_t)d * 512 + k]);
        acc = fmaf(v, v, acc);
    }
    s[t] = acc;
    __syncthreads();
    if (t < 64) {
        float a = 0.f;
        #pragma unroll
        for (int g2 = 0; g2 < 16; ++g2) a += s[g2 * 64 + k];
        int ok = (a >= 100.f && a <= 2000.f) ? 1 : 0;
        unsigned long long m = __ballot(ok);
        if (k == 0) {
            *flag = (m == ~0ull) ? 1 : 0;
            *scnt = 0;
        }
    }
}

// ---------------------------------------------------------------------------
// FUSED prep: one launch, role-split by blockIdx. NO cross-role dependencies.
// ---------------------------------------------------------------------------
__global__ __launch_bounds__(256) void k_prepAll(
        const void* __restrict__ We, const void* __restrict__ be,
        const void* __restrict__ Wd, const void* __restrict__ bd,
        const void* __restrict__ cb, const int* __restrict__ flagp,
        float* __restrict__ cWe, float* __restrict__ cbe,
        float* __restrict__ cWd, float* __restrict__ cbd,
        float* __restrict__ cbT, unsigned short* __restrict__ cbHS,
        unsigned short* __restrict__ cbLS,
        float* __restrict__ w2, double* __restrict__ w2d,
        float* __restrict__ U) {
    __shared__ float tile[64][65];
    __shared__ double sd[256];
    const int bid = blockIdx.x;
    const int t = threadIdx.x;
    const int flag = *flagp;

    if (bid < 195) {
        // ---- canonW ----
        int e = bid * 256 + t;
        if (e < 24576)       cWe[e]         = ldin(We, e, flag);
        else if (e < 25088)  cbe[e - 24576] = ldin(be, e - 24576, flag);
        else if (e < 49664)  cWd[e - 25088] = ldin(Wd, e - 25088, flag);
        else if (e < 49667)  cbd[e - 49664] = ldin(bd, e - 49664, flag);
    } else if (bid < 259) {
        // ---- prepcb ----
        const int bb = bid - 195;
        const int D0 = (bb >> 3) * 64, K0 = (bb & 7) * 64;
        for (int it = 0; it < 16; ++it) {
            int r = (t >> 6) + 4 * it, c = t & 63;
            tile[r][c] = ldin(cb, (size_t)(D0 + r) * 512 + K0 + c, flag);
        }
        __syncthreads();
        for (int it = 0; it < 16; ++it) {
            int r = (t >> 6) + 4 * it, c = t & 63;
            float v = tile[c][r];
            int k = K0 + r, d = D0 + c;
            cbT[(size_t)k * 512 + d] = v;
            size_t o2 = swzoff(k, d);
            unsigned short h = f2bf(v);
            cbHS[o2] = h;
            cbLS[o2] = f2bf(v - bfu(h));
        }
    } else if (bid < 267) {
        // ---- w2 ----
        const int k = (bid - 259) * 64 + (t & 63);
        const int g = t >> 6;                  // 4 groups x 128 d
        double acc = 0.0;
        for (int d = g * 128; d < g * 128 + 128; ++d) {
            double v = (double)ldin(cb, (size_t)d * 512 + k, flag);
            acc += v * v;
        }
        sd[t] = acc;
        __syncthreads();
        if (t < 64) {
            double a = sd[t] + sd[t + 64] + sd[t + 128] + sd[t + 192];
            w2[k] = (float)a;
            w2d[k] = a;
        }
    } else {
        // ---- udec: U[k][c*16+u*4+v] = sum_d cb[d][k]*Wd[c][d][3-u][3-v]+bd[c]
        const int kk = (bid - 267) * 4 + (t >> 6);
        const int lane = t & 63;
        const int j = lane >> 2, dpart = lane & 3;
        const int u = (j >> 2) & 3, v = j & 3;
        int woff[3];
        #pragma unroll
        for (int m = 0; m < 3; ++m) woff[m] = m * 8192 + (3 - u) * 4 + (3 - v);
        float a0 = 0.f, a1 = 0.f, a2 = 0.f;
        for (int i = 0; i < 128; ++i) {
            int d = dpart * 128 + i;
            float cw = ldin(cb, (size_t)d * 512 + kk, flag);
            a0 = fmaf(cw, ldin(Wd, (size_t)(woff[0] + d * 16), flag), a0);
            a1 = fmaf(cw, ldin(Wd, (size_t)(woff[1] + d * 16), flag), a1);
            a2 = fmaf(cw, ldin(Wd, (size_t)(woff[2] + d * 16), flag), a2);
        }
        a0 += __shfl_xor(a0, 1); a0 += __shfl_xor(a0, 2);
        a1 += __shfl_xor(a1, 1); a1 += __shfl_xor(a1, 2);
        a2 += __shfl_xor(a2, 1); a2 += __shfl_xor(a2, 2);
        if (dpart == 0) {
            U[kk * 48 +  0 + j] = a0 + ldin(bd, 0, flag);
            U[kk * 48 + 16 + j] = a1 + ldin(bd, 1, flag);
            U[kk * 48 + 32 + j] = a2 + ldin(bd, 2, flag);
        }
    }
}

// ---------------------------------------------------------------------------
// k_main helpers — EXACT r8 (123us) version.
// zq pair layout: zH [64][40] shorts at 0, zL at +2560; pair = 5120 shorts.
// conv: thread = 1 d-channel (t&31) x 4 positions (((t>>5)&15)*4).
// ---------------------------------------------------------------------------
static __device__ __forceinline__ void conv_step(
        const float* __restrict__ patch, const float* __restrict__ cWe,
        const float* __restrict__ cbe, int dc, int t,
        unsigned short* __restrict__ zq,
        float* __restrict__ out_z, int b, int SP0) {
    const int cd = t & 31;
    const int ps = ((t >> 5) & 15) * 4;       // 16 groups x 4 positions
    const float4* wv = (const float4*)(cWe + (size_t)(dc + cd) * 48);
    const float bias = cbe[dc + cd];
    float za[4];
    #pragma unroll
    for (int p = 0; p < 4; ++p) za[p] = bias;
    #pragma unroll
    for (int q4 = 0; q4 < 12; ++q4) {
        float4 wq = wv[q4];
        #pragma unroll
        for (int p = 0; p < 4; ++p) {
            float4 v = ((const float4*)(patch + (ps + p) * 48))[q4];
            za[p] = fmaf(v.x, wq.x, za[p]);
            za[p] = fmaf(v.y, wq.y, za[p]);
            za[p] = fmaf(v.z, wq.z, za[p]);
            za[p] = fmaf(v.w, wq.w, za[p]);
        }
    }
    float zf[4];
    #pragma unroll
    for (int p = 0; p < 4; ++p) {
        float z = fmaxf(za[p], 0.f);
        unsigned short h = f2bf(z);
        unsigned short l = f2bf(z - bfu(h));
        zq[(ps + p) * 40 + cd] = h;
        zq[2560 + (ps + p) * 40 + cd] = l;
        zf[p] = bfu(h) + bfu(l);
    }
    size_t zbase = (size_t)(b * 512 + dc + cd) * 1024 + SP0 + ps;
    *(float4*)(out_z + zbase) = (float4){zf[0], zf[1], zf[2], zf[3]};
}

// Each wave handles code-tiles wave*4+j (j=0..3): acc[4 mt][4 j].
static __device__ __forceinline__ void mfma_step(
        const unsigned short* __restrict__ zq,
        const unsigned short* __restrict__ cbHS,
        const unsigned short* __restrict__ cbLS,
        int dcPrev, int wave, int quad, int lcol, int flag, floatx4 (&acc)[4][4]) {
    const int lane = quad * 16 + lcol;
    short8 aH[4], aL[4];
    #pragma unroll
    for (int mt = 0; mt < 4; ++mt) {
        aH[mt] = *(const short8*)(zq + (mt * 16 + lcol) * 40 + quad * 8);
        aL[mt] = *(const short8*)(zq + 2560 + (mt * 16 + lcol) * 40 + quad * 8);
    }
    const unsigned short* fbH = cbHS + (size_t)dcPrev * 512 + (size_t)(wave * 4) * 512 + lane * 8;
    #pragma unroll
    for (int j = 0; j < 4; ++j) {
        short8 bH = *(const short8*)(fbH + j * 512);
        #pragma unroll
        for (int mt = 0; mt < 4; ++mt) {
            acc[mt][j] = __builtin_amdgcn_mfma_f32_16x16x32_bf16(aH[mt], bH, acc[mt][j], 0, 0, 0);
            acc[mt][j] = __builtin_amdgcn_mfma_f32_16x16x32_bf16(aL[mt], bH, acc[mt][j], 0, 0, 0);
        }
    }
    if (!flag) {   // fp32 inputs: third term zh*cbL
        const unsigned short* fbL = cbLS + (size_t)dcPrev * 512 + (size_t)(wave * 4) * 512 + lane * 8;
        #pragma unroll
        for (int j = 0; j < 4; ++j) {
            short8 bL = *(const short8*)(fbL + j * 512);
            #pragma unroll
            for (int mt = 0; mt < 4; ++mt)
                acc[mt][j] = __builtin_amdgcn_mfma_f32_16x16x32_bf16(aH[mt], bL, acc[mt][j], 0, 0, 0);
        }
    }
}

// best/second combine: (a1,ak,a2) <- merge (o1,ok,o2). Order-independent
// tournament (ties -> gap 0), so reshaping the reduction tree is safe.
static __device__ __forceinline__ void bmerge(float& a1, int& ak, float& a2,
                                              float o1, int ok, float o2) {
    if (o1 < a1)      { a2 = fminf(a1, o2); a1 = o1; ak = ok; }
    else if (o1 > a1) { a2 = fminf(a2, o1); }
    else              { a2 = a1; if (ok < ak) ak = ok; }
}

// ---------------------------------------------------------------------------
// FUSED main v13 = r8 (v10) VERBATIM: 512 blocks x 512 threads, 64-pos tiles,
// 16 waves/CU, coalesced B — the proven 123us configuration. v12's 2-channel
// conv REVERTED (doubled live weight regs under VGPR=64 -> load-use stalls,
// 2x regression with identical occupancy/traffic).
// ---------------------------------------------------------------------------
__global__ __launch_bounds__(512, 4) void k_main(
        const void* __restrict__ x, const float* __restrict__ cWe,
        const float* __restrict__ cbe, const int* __restrict__ flagp,
        const unsigned short* __restrict__ cbHS, const unsigned short* __restrict__ cbLS,
        const float* __restrict__ cbT, const float* __restrict__ w2,
        float* __restrict__ out_z, float* __restrict__ out_e,
        int* __restrict__ idx, int* __restrict__ scnt, int* __restrict__ spos,
        int skipTail) {
    __shared__ __align__(16) char smc[32768];
    float* patch = (float*)smc;                               // [64][48] fp32
    unsigned short* zb = (unsigned short*)(smc + 12288);      // 2 pairs x 5120 shorts

    const int t = threadIdx.x;
    const int bid = blockIdx.x;
    const int q = ((bid & 7) << 6) | (bid >> 3);   // XCD co-location swizzle
    const int P0 = q * 64;
    const int b = P0 >> 10, SP0 = P0 & 1023;
    const int flag = *flagp;
    const int wave = t >> 6, lane = t & 63;
    const int quad = lane >> 4, lcol = lane & 15;

    // stage x patches once
    for (int e = t; e < 3072; e += 512) {
        int pid = e / 48, kk = e % 48;
        int c = kk >> 4, r = (kk >> 2) & 3, s = kk & 3;
        int pos = P0 + pid;
        int bb = pos >> 10, sp = pos & 1023, i = sp >> 5, j = sp & 31;
        patch[pid * 48 + kk] = ldin(x, ((bb * 3 + c) * 128 + (i * 4 + r)) * 128 + (j * 4 + s), flag);
    }

    floatx4 acc[4][4];
    #pragma unroll
    for (int mt = 0; mt < 4; ++mt)
        #pragma unroll
        for (int j = 0; j < 4; ++j) acc[mt][j] = (floatx4){0.f, 0.f, 0.f, 0.f};

    ldsbar();
    conv_step(patch, cWe, cbe, 0, t, zb, out_z, b, SP0);      // chunk 0 -> pair 0
    for (int dc = 32; dc < 512; dc += 32) {
        ldsbar();
        const int p = (dc >> 5) & 1;
        conv_step(patch, cWe, cbe, dc, t, zb + p * 5120, out_z, b, SP0);
        mfma_step(zb + (p ^ 1) * 5120, cbHS, cbLS, dc - 32, wave, quad, lcol, flag, acc);
    }
    ldsbar();
    mfma_step(zb + 5120, cbHS, cbLS, 480, wave, quad, lcol, flag, acc);

    // ---- epilogue: per-lane best/second over its 4 codes, then shuffle ----
    float s1[4][4], s2[4][4]; int k1[4][4];
    #pragma unroll
    for (int mt = 0; mt < 4; ++mt)
        #pragma unroll
        for (int r = 0; r < 4; ++r) { s1[mt][r] = 1e30f; s2[mt][r] = 1e30f; k1[mt][r] = 511; }
    #pragma unroll
    for (int j = 0; j < 4; ++j) {
        int code = (wave * 4 + j) * 16 + lcol;
        float wk = w2[code];
        #pragma unroll
        for (int mt = 0; mt < 4; ++mt)
            #pragma unroll
            for (int r = 0; r < 4; ++r) {
                float s = wk - 2.f * acc[mt][j][r];
                bmerge(s1[mt][r], k1[mt][r], s2[mt][r], s, code, 1e30f);
            }
    }
    // overlay reduction arrays on patch region (patch dead after last conv+bar)
    float* sS1 = (float*)smc;             // [64 pos][8 wave]
    int*   sK1 = (int*)(smc + 2048);
    float* sS2 = (float*)(smc + 4096);
    int*   ii  = (int*)(smc + 6144);      // [64]
    #pragma unroll
    for (int mt = 0; mt < 4; ++mt)
        #pragma unroll
        for (int r = 0; r < 4; ++r) {
            float a1 = s1[mt][r], a2 = s2[mt][r]; int ak = k1[mt][r];
            #pragma unroll
            for (int m = 1; m < 16; m <<= 1) {
                float o1 = __shfl_xor(a1, m);
                float o2 = __shfl_xor(a2, m);
                int   ok = __shfl_xor(ak, m);
                bmerge(a1, ak, a2, o1, ok, o2);
            }
            if (lcol == 0) {
                int pos = mt * 16 + quad * 4 + r;
                sS1[pos * 8 + wave] = a1;
                sK1[pos * 8 + wave] = ak;
                sS2[pos * 8 + wave] = a2;
            }
        }
    __syncthreads();
    if (t < 64) {
        float a1 = sS1[t * 8]; int ak = sK1[t * 8]; float a2 = sS2[t * 8];
        #pragma unroll
        for (int w = 1; w < 8; ++w)
            bmerge(a1, ak, a2, sS1[t * 8 + w], sK1[t * 8 + w], sS2[t * 8 + w]);
        ak &= 511;
        ii[t] = ak;
        unsigned int flagged = 0u;
        if (a2 - a1 < EPS_GAP) {
            int slot = atomicAdd(scnt, 1);
            if (slot < MAXSUS) { spos[slot] = P0 + t; flagged = 1u; }
        }
        idx[P0 + t] = (int)((unsigned)ak | (flagged << 31));
    }
    __syncthreads();

    // ---- fused emb: out_e[b][d][SP0+sp] = cbT[ii[sp]][d] ----
    const int sp = t & 63, dq = t >> 6;   // 8 groups x 64 d
    const float* row = cbT + (size_t)ii[sp] * 512;
    const size_t obase = ((size_t)b * 512) * 1024 + SP0 + sp;
    for (int d0 = dq * 64; d0 < dq * 64 + 64; d0 += 4) {
        if (skipTail && b == 31 && d0 >= 448) break;
        float4 v = *(const float4*)(row + d0);
        out_e[obase + (size_t)(d0    ) * 1024] = v.x;
        out_e[obase + (size_t)(d0 + 1) * 1024] = v.y;
        out_e[obase + (size_t)(d0 + 2) * 1024] = v.z;
        out_e[obase + (size_t)(d0 + 3) * 1024] = v.w;
    }
}

// ---------------------------------------------------------------------------
// FUSED post: recon (bid 0..127) ∥ rescore (bid 128..383) in one launch.
// Rescore widened to 256 blocks (was 128) to halve the serial-tail cost when
// the suspect count is large.
// ---------------------------------------------------------------------------
__global__ __launch_bounds__(256) void k_post(
        const float* __restrict__ out_z, const void* __restrict__ cb,
        const double* __restrict__ w2d, int* __restrict__ idx,
        const int* __restrict__ scnt, const int* __restrict__ spos,
        const float* __restrict__ U, const int* __restrict__ flagp,
        float* __restrict__ out_e, float* __restrict__ out_r, int skipTail) {
    __shared__ float zsh[512];
    __shared__ float rs[256];
    __shared__ int rk[256];
    __shared__ int bc[2];
    const int bid = blockIdx.x;
    const int t = threadIdx.x;

    if (bid < 128) {
        // ---- recon role ----
        const int pos = bid * 256 + t;
        const int v0 = idx[pos];
        if (v0 >= 0) {
            const int id = v0 & 511;
            const int b = pos >> 10, sp = pos & 1023, i = sp >> 5, j = sp & 31;
            const float* u = &U[(size_t)id * 48];
            #pragma unroll
            for (int c = 0; c < 3; ++c)
                #pragma unroll
                for (int uu = 0; uu < 4; ++uu) {
                    float4 q = *(const float4*)(&u[c * 16 + uu * 4]);
                    float4 o;
                    o.x = 1.f / (1.f + __expf(-q.x));
                    o.y = 1.f / (1.f + __expf(-q.y));
                    o.z = 1.f / (1.f + __expf(-q.z));
                    o.w = 1.f / (1.f + __expf(-q.w));
                    *(float4*)(&out_r[((size_t)((b * 3 + c) * 128) + (i * 4 + uu)) * 128 + j * 4]) = o;
                }
        }
        return;
    }

    // ---- rescore role (256 blocks) ----
    const int flag = *flagp;
    int n = *scnt; if (n > MAXSUS) n = MAXSUS;
    for (int s = bid - 128; s < n; s += 256) {
        int p = spos[s] & 32767;
        int b = p >> 10, sp = p & 1023;
        __syncthreads();
        zsh[t]       = out_z[(size_t)(b * 512 + t) * 1024 + sp];
        zsh[t + 256] = out_z[(size_t)(b * 512 + t + 256) * 1024 + sp];
        __syncthreads();
        float bs = 1e30f; int bk = 511;
        for (int cc = 0; cc < 2; ++cc) {
            int k = t + cc * 256;
            double a = 0.0;
            for (int d = 0; d < 512; ++d)
                a = fma((double)zsh[d], (double)ldin(cb, (size_t)d * 512 + k, flag), a);
            float sc = (float)(w2d[k] - 2.0 * a);
            if (sc < bs || (sc == bs && k < bk)) { bs = sc; bk = k; }
        }
        rs[t] = bs; rk[t] = bk;
        __syncthreads();
        for (int str = 128; str > 0; str >>= 1) {
            if (t < str) {
                float so = rs[t + str]; int ko = rk[t + str];
                if (so < rs[t] || (so == rs[t] && ko < rk[t])) { rs[t] = so; rk[t] = ko; }
            }
            __syncthreads();
        }
        if (t == 0) {
            int kstar = rk[0] & 511;
            int old = idx[p] & 511;
            bc[0] = kstar; bc[1] = (kstar != old);
            idx[p] = kstar;                       // clears suspect flag too
        }
        __syncthreads();
        const int kk = bc[0];
        if (bc[1]) {
            for (int d = t; d < 512; d += 256) {
                if (skipTail && b == 31 && d >= 448) continue;
                out_e[(size_t)(b * 512 + d) * 1024 + sp] = ldin(cb, (size_t)d * 512 + kk, flag);
            }
        }
        // recon for this suspect (recon role skipped it) — always write
        if (t < 48) {
            float q = U[(size_t)kk * 48 + t];
            float o = 1.f / (1.f + __expf(-q));
            int c = t >> 4, uu = (t >> 2) & 3, vv = t & 3;
            int i = sp >> 5, j = sp & 31;
            out_r[((size_t)((b * 3 + c) * 128) + (i * 4 + uu)) * 128 + j * 4 + vv] = o;
        }
    }
}

// ---------------------------------------------------------------------------
// Widened fixup: 64 blocks, one d-row each. Coalesced idx read + row write.
// ---------------------------------------------------------------------------
__global__ __launch_bounds__(1024) void k_fixup(
        const void* __restrict__ cb, const int* __restrict__ flagp,
        const int* __restrict__ idx, float* __restrict__ out_e) {
    const int t = threadIdx.x;
    const int d = 448 + blockIdx.x;
    const int flag = *flagp;
    const int id = idx[31744 + t] & 511;
    out_e[((size_t)(31 * 512 + d)) * 1024 + t] = ldin(cb, (size_t)d * 512 + id, flag);
}

// ---------------------------------------------------------------------------
extern "C" void kernel_launch(void* const* d_in, const int* in_sizes, int n_in,
                              void* d_out, int out_size, void* d_ws, size_t ws_size,
                              hipStream_t stream) {
    const void* x  = d_in[0];
    const void* We = d_in[1];
    const void* be = d_in[2];
    const void* Wd = d_in[3];
    const void* bd = d_in[4];
    const void* cb = d_in[5];

    float* out   = (float*)d_out;
    float* out_r = out;                       // 1,572,864 fp32 (6.29 MB)
    float* out_z = out + 1572864;             // 16,777,216 fp32
    float* out_e = out + 18350080;            // 16,777,216 fp32

    // Read-mostly tables in out_r (recon overwrites during k_post; nothing in
    // k_post reads them — rescore uses raw cb):
    char* Rb = (char*)out_r;
    float* cbT          = (float*)(Rb);                    // 1,048,576 B
    float* cWe          = (float*)(Rb + 1048576);          //    98,304 B
    float* cbe          = (float*)(Rb + 1146880);          //     2,048 B
    float* cWd          = (float*)(Rb + 1148928);          //    98,304 B
    float* cbd          = (float*)(Rb + 1247232);          //        64 B
    unsigned short* cbHS= (unsigned short*)(Rb + 1247296); //   524,288 B (swizzled)
    unsigned short* cbLS= (unsigned short*)(Rb + 1771584); //   524,288 B (swizzled)

    // Tail scratch: prefer d_ws; else last 256 KB of out_e (fixup required).
    int tailWS = (ws_size >= 262144) ? 1 : 0;
    char* Tbase = tailWS ? (char*)d_ws : ((char*)out_e + 66846720);
    int skipTail = tailWS ? 0 : 1;
    int*    idx  = (int*)   (Tbase);            // 131,072 B
    float*  U    = (float*) (Tbase + 131072);   //  98,304 B
    float*  w2   = (float*) (Tbase + 229376);   //   2,048 B
    double* w2d  = (double*)(Tbase + 231424);   //   4,096 B
    int*    flag = (int*)   (Tbase + 235520);   //      64 B
    int*    scnt = (int*)   (Tbase + 235584);   //      64 B
    int*    spos = (int*)   (Tbase + 235648);   //  16,384 B

    k_sniff<<<1, 1024, 0, stream>>>(cb, flag, scnt);
    k_prepAll<<<395, 256, 0, stream>>>(We, be, Wd, bd, cb, flag,
                                       cWe, cbe, cWd, cbd,
                                       cbT, cbHS, cbLS, w2, w2d, U);
    k_main<<<512, 512, 0, stream>>>(x, cWe, cbe, flag, cbHS, cbLS, cbT, w2,
                                    out_z, out_e, idx, scnt, spos, skipTail);
    k_post<<<384, 256, 0, stream>>>(out_z, cb, w2d, idx, scnt, spos, U, flag,
                                    out_e, out_r, skipTail);
    if (skipTail)
        k_fixup<<<64, 1024, 0, stream>>>(cb, flag, idx, out_e);
}

// Round 12
// 251.346 us; speedup vs baseline: 1.6010x; 1.1107x over previous
//
#include <hip/hip_runtime.h>
#include <hip/hip_bf16.h>

// B=32, C=3, H=W=128, D=512, K=512, S=4, NPOS=32768
#define NPOS 32768
#define EPS_GAP 4e-3f
#define MAXSUS 4096

typedef __attribute__((ext_vector_type(8))) short short8;
typedef __attribute__((ext_vector_type(4))) float floatx4;

static __device__ __forceinline__ float bfu(unsigned short h) {
    return __uint_as_float(((unsigned int)h) << 16);
}
static __device__ __forceinline__ unsigned short f2bf(float f) {
    unsigned int u = __float_as_uint(f);
    u = (u + 0x7fffu + ((u >> 16) & 1u)) >> 16;   // RNE
    return (unsigned short)u;
}
static __device__ __forceinline__ float ldin(const void* p, size_t i, int flag) {
    return flag ? bfu(((const unsigned short*)p)[i]) : ((const float*)p)[i];
}

// LDS-only barrier: drains ds ops (lgkmcnt) but leaves global loads/stores
// in flight across the barrier (no vmcnt(0) drain).
static __device__ __forceinline__ void ldsbar() {
    asm volatile("s_waitcnt lgkmcnt(0)" ::: "memory");
    __builtin_amdgcn_s_barrier();
    asm volatile("" ::: "memory");
}

// Swizzled B-fragment offset for the CODEBOOK (units: shorts).
static __device__ __forceinline__ size_t swzoff(int k, int d) {
    return (size_t)(d >> 5) * 16384 + (size_t)(k >> 4) * 512
         + (size_t)((((d >> 3) & 3) * 16 + (k & 15)) * 8) + (d & 7);
}

// ---------------------------------------------------------------------------
// Sniff: decide bf16 vs fp32 input encoding from codebook column norms.
// ---------------------------------------------------------------------------
__global__ __launch_bounds__(1024) void k_sniff(const void* __restrict__ cb,
                                                int* __restrict__ flag,
                                                int* __restrict__ scnt) {
    __shared__ float s[1024];
    const int t = threadIdx.x;
    const int k = t & 63, g = t >> 6;          // 16 groups x 32 d
    const unsigned short* u = (const unsigned short*)cb;
    float acc = 0.f;
    for (int d = g * 32; d < g * 32 + 32; ++d) {
        float v = bfu(u[(size_t)d * 512 + k]);
        acc = fmaf(v, v, acc);
    }
    s[t] = acc;
    __syncthreads();
    if (t < 64) {
        float a = 0.f;
        #pragma unroll
        for (int g2 = 0; g2 < 16; ++g2) a += s[g2 * 64 + k];
        int ok = (a >= 100.f && a <= 2000.f) ? 1 : 0;
        unsigned long long m = __ballot(ok);
        if (k == 0) {
            *flag = (m == ~0ull) ? 1 : 0;
            *scnt = 0;
        }
    }
}

// ---------------------------------------------------------------------------
// FUSED prep: one launch, role-split by blockIdx. NO cross-role dependencies.
//   bid   0..194 : canonW   (We/be/Wd/bd -> canonical fp32)       [reads raw]
//   bid 195..258 : prepcb   (cb -> cbT; cbHS/cbLS swizzled bf16)  [reads raw cb]
//   bid 259..266 : w2       (column norms)                        [reads raw cb]
//   bid 267..394 : udec     (decoder LUT U[k][48])                [reads raw]
//   bid 395..402 : weswz    (We -> H/L bf16 B-fragment tables, K-padded to 64)
// ---------------------------------------------------------------------------
__global__ __launch_bounds__(256) void k_prepAll(
        const void* __restrict__ We, const void* __restrict__ be,
        const void* __restrict__ Wd, const void* __restrict__ bd,
        const void* __restrict__ cb, const int* __restrict__ flagp,
        float* __restrict__ cWe, float* __restrict__ cbe,
        float* __restrict__ cWd, float* __restrict__ cbd,
        float* __restrict__ cbT, unsigned short* __restrict__ cbHS,
        unsigned short* __restrict__ cbLS,
        unsigned short* __restrict__ WeswzH, unsigned short* __restrict__ WeswzL,
        float* __restrict__ w2, double* __restrict__ w2d,
        float* __restrict__ U) {
    __shared__ float tile[64][65];
    __shared__ double sd[256];
    const int bid = blockIdx.x;
    const int t = threadIdx.x;
    const int flag = *flagp;

    if (bid < 195) {
        // ---- canonW ----
        int e = bid * 256 + t;
        if (e < 24576)       cWe[e]         = ldin(We, e, flag);
        else if (e < 25088)  cbe[e - 24576] = ldin(be, e - 24576, flag);
        else if (e < 49664)  cWd[e - 25088] = ldin(Wd, e - 25088, flag);
        else if (e < 49667)  cbd[e - 49664] = ldin(bd, e - 49664, flag);
    } else if (bid < 259) {
        // ---- prepcb ----
        const int bb = bid - 195;
        const int D0 = (bb >> 3) * 64, K0 = (bb & 7) * 64;
        for (int it = 0; it < 16; ++it) {
            int r = (t >> 6) + 4 * it, c = t & 63;
            tile[r][c] = ldin(cb, (size_t)(D0 + r) * 512 + K0 + c, flag);
        }
        __syncthreads();
        for (int it = 0; it < 16; ++it) {
            int r = (t >> 6) + 4 * it, c = t & 63;
            float v = tile[c][r];
            int k = K0 + r, d = D0 + c;
            cbT[(size_t)k * 512 + d] = v;
            size_t o2 = swzoff(k, d);
            unsigned short h = f2bf(v);
            cbHS[o2] = h;
            cbLS[o2] = f2bf(v - bfu(h));
        }
    } else if (bid < 267) {
        // ---- w2 ----
        const int k = (bid - 259) * 64 + (t & 63);
        const int g = t >> 6;                  // 4 groups x 128 d
        double acc = 0.0;
        for (int d = g * 128; d < g * 128 + 128; ++d) {
            double v = (double)ldin(cb, (size_t)d * 512 + k, flag);
            acc += v * v;
        }
        sd[t] = acc;
        __syncthreads();
        if (t < 64) {
            double a = sd[t] + sd[t + 64] + sd[t + 128] + sd[t + 192];
            w2[k] = (float)a;
            w2d[k] = a;
        }
    } else if (bid < 395) {
        // ---- udec: U[k][c*16+u*4+v] = sum_d cb[d][k]*Wd[c][d][3-u][3-v]+bd[c]
        const int kk = (bid - 267) * 4 + (t >> 6);
        const int lane = t & 63;
        const int j = lane >> 2, dpart = lane & 3;
        const int u = (j >> 2) & 3, v = j & 3;
        int woff[3];
        #pragma unroll
        for (int m = 0; m < 3; ++m) woff[m] = m * 8192 + (3 - u) * 4 + (3 - v);
        float a0 = 0.f, a1 = 0.f, a2 = 0.f;
        for (int i = 0; i < 128; ++i) {
            int d = dpart * 128 + i;
            float cw = ldin(cb, (size_t)d * 512 + kk, flag);
            a0 = fmaf(cw, ldin(Wd, (size_t)(woff[0] + d * 16), flag), a0);
            a1 = fmaf(cw, ldin(Wd, (size_t)(woff[1] + d * 16), flag), a1);
            a2 = fmaf(cw, ldin(Wd, (size_t)(woff[2] + d * 16), flag), a2);
        }
        a0 += __shfl_xor(a0, 1); a0 += __shfl_xor(a0, 2);
        a1 += __shfl_xor(a1, 1); a1 += __shfl_xor(a1, 2);
        a2 += __shfl_xor(a2, 1); a2 += __shfl_xor(a2, 2);
        if (dpart == 0) {
            U[kk * 48 +  0 + j] = a0 + ldin(bd, 0, flag);
            U[kk * 48 + 16 + j] = a1 + ldin(bd, 1, flag);
            U[kk * 48 + 32 + j] = a2 + ldin(bd, 2, flag);
        }
    } else {
        // ---- weswz: We[d][q<48] (q 48..63 zero) -> H/L B-fragment tables.
        // Element (d,q) at: ((d>>5)*2+((d>>4)&1))*1024 + (q>>5)*512
        //                   + (((q>>3)&3)*16 + (d&15))*8 + (q&7)
        const int bid2 = bid - 395;            // 0..7
        for (int it = 0; it < 16; ++it) {
            int e = bid2 * 4096 + it * 256 + t;    // over 512*64
            int d = e >> 6, q = e & 63;
            float w = (q < 48) ? ldin(We, (size_t)d * 48 + q, flag) : 0.f;
            unsigned short h = f2bf(w);
            unsigned short l = f2bf(w - bfu(h));
            size_t off = (size_t)((d >> 5) * 2 + ((d >> 4) & 1)) * 1024
                       + (size_t)(q >> 5) * 512
                       + (size_t)((((q >> 3) & 3) * 16 + (d & 15)) * 8) + (q & 7);
            WeswzH[off] = h;
            WeswzL[off] = l;
        }
    }
}

// ---------------------------------------------------------------------------
// k_main v14: conv moved to MFMA. Per chunk, 8 waves = 8 (mt,nt) tiles of
// Z[64 pos][32 d] = patch[64x48pad64] x We[48pad64 x 32], split-precision bf16.
// For flag=1 (bf16 inputs) patchL=WeL=0 -> single exact H*H term.
// C layout (verified by passing epilogue): col=lcol -> d, row=quad*4+r -> pos.
// zq [pos][40] H/L layout unchanged -> mfma_step byte-identical to r8.
// ---------------------------------------------------------------------------
static __device__ __forceinline__ void conv_mfma(
        const unsigned short* __restrict__ patchH, const unsigned short* __restrict__ patchL,
        const unsigned short* __restrict__ WeH, const unsigned short* __restrict__ WeL,
        const float* __restrict__ cbe, int dc, int wave, int lane, int flag,
        unsigned short* __restrict__ zq, float* __restrict__ out_z, int b, int SP0) {
    const int mt = wave >> 1, nt = wave & 1;
    const int quad = lane >> 4, lcol = lane & 15;
    const int row = mt * 16 + lcol;
    short8 aH0 = *(const short8*)(patchH + row * 72 + quad * 8);
    short8 aH1 = *(const short8*)(patchH + row * 72 + 32 + quad * 8);
    const unsigned short* wb = WeH + (size_t)((dc >> 5) * 2 + nt) * 1024 + lane * 8;
    short8 bH0 = *(const short8*)(wb);
    short8 bH1 = *(const short8*)(wb + 512);
    floatx4 c = (floatx4){0.f, 0.f, 0.f, 0.f};
    c = __builtin_amdgcn_mfma_f32_16x16x32_bf16(aH0, bH0, c, 0, 0, 0);
    c = __builtin_amdgcn_mfma_f32_16x16x32_bf16(aH1, bH1, c, 0, 0, 0);
    if (!flag) {   // fp32 inputs: add L*H and H*L terms
        short8 aL0 = *(const short8*)(patchL + row * 72 + quad * 8);
        short8 aL1 = *(const short8*)(patchL + row * 72 + 32 + quad * 8);
        const unsigned short* wl = WeL + (size_t)((dc >> 5) * 2 + nt) * 1024 + lane * 8;
        short8 bL0 = *(const short8*)(wl);
        short8 bL1 = *(const short8*)(wl + 512);
        c = __builtin_amdgcn_mfma_f32_16x16x32_bf16(aL0, bH0, c, 0, 0, 0);
        c = __builtin_amdgcn_mfma_f32_16x16x32_bf16(aL1, bH1, c, 0, 0, 0);
        c = __builtin_amdgcn_mfma_f32_16x16x32_bf16(aH0, bL0, c, 0, 0, 0);
        c = __builtin_amdgcn_mfma_f32_16x16x32_bf16(aH1, bL1, c, 0, 0, 0);
    }
    const int d = nt * 16 + lcol;
    const float bias = cbe[dc + d];
    const int p0 = mt * 16 + quad * 4;        // 4 consecutive positions
    float zf[4];
    #pragma unroll
    for (int r = 0; r < 4; ++r) {
        float z = fmaxf(c[r] + bias, 0.f);
        unsigned short h = f2bf(z);
        unsigned short l = f2bf(z - bfu(h));
        zq[(p0 + r) * 40 + d] = h;
        zq[2560 + (p0 + r) * 40 + d] = l;
        zf[r] = bfu(h) + bfu(l);
    }
    *(float4*)(out_z + (size_t)(b * 512 + dc + d) * 1024 + SP0 + p0) =
        (float4){zf[0], zf[1], zf[2], zf[3]};
}

// Each wave handles code-tiles wave*4+j (j=0..3): acc[4 mt][4 j]. (r8 verbatim)
static __device__ __forceinline__ void mfma_step(
        const unsigned short* __restrict__ zq,
        const unsigned short* __restrict__ cbHS,
        const unsigned short* __restrict__ cbLS,
        int dcPrev, int wave, int quad, int lcol, int flag, floatx4 (&acc)[4][4]) {
    const int lane = quad * 16 + lcol;
    short8 aH[4], aL[4];
    #pragma unroll
    for (int mt = 0; mt < 4; ++mt) {
        aH[mt] = *(const short8*)(zq + (mt * 16 + lcol) * 40 + quad * 8);
        aL[mt] = *(const short8*)(zq + 2560 + (mt * 16 + lcol) * 40 + quad * 8);
    }
    const unsigned short* fbH = cbHS + (size_t)dcPrev * 512 + (size_t)(wave * 4) * 512 + lane * 8;
    #pragma unroll
    for (int j = 0; j < 4; ++j) {
        short8 bH = *(const short8*)(fbH + j * 512);
        #pragma unroll
        for (int mt = 0; mt < 4; ++mt) {
            acc[mt][j] = __builtin_amdgcn_mfma_f32_16x16x32_bf16(aH[mt], bH, acc[mt][j], 0, 0, 0);
            acc[mt][j] = __builtin_amdgcn_mfma_f32_16x16x32_bf16(aL[mt], bH, acc[mt][j], 0, 0, 0);
        }
    }
    if (!flag) {   // fp32 inputs: third term zh*cbL
        const unsigned short* fbL = cbLS + (size_t)dcPrev * 512 + (size_t)(wave * 4) * 512 + lane * 8;
        #pragma unroll
        for (int j = 0; j < 4; ++j) {
            short8 bL = *(const short8*)(fbL + j * 512);
            #pragma unroll
            for (int mt = 0; mt < 4; ++mt)
                acc[mt][j] = __builtin_amdgcn_mfma_f32_16x16x32_bf16(aH[mt], bL, acc[mt][j], 0, 0, 0);
        }
    }
}

// best/second combine: (a1,ak,a2) <- merge (o1,ok,o2). Order-independent
// tournament (ties -> gap 0), so reshaping the reduction tree is safe.
static __device__ __forceinline__ void bmerge(float& a1, int& ak, float& a2,
                                              float o1, int ok, float o2) {
    if (o1 < a1)      { a2 = fminf(a1, o2); a1 = o1; ak = ok; }
    else if (o1 > a1) { a2 = fminf(a2, o1); }
    else              { a2 = a1; if (ok < ak) ak = ok; }
}

// ---------------------------------------------------------------------------
// LDS: patchH [64][72]sh 9216B | patchL 9216B | zb 2 pairs x 10240B = 38912B.
// ---------------------------------------------------------------------------
__global__ __launch_bounds__(512, 4) void k_main(
        const void* __restrict__ x, const unsigned short* __restrict__ WeswzH,
        const unsigned short* __restrict__ WeswzL,
        const float* __restrict__ cbe, const int* __restrict__ flagp,
        const unsigned short* __restrict__ cbHS, const unsigned short* __restrict__ cbLS,
        const float* __restrict__ cbT, const float* __restrict__ w2,
        float* __restrict__ out_z, float* __restrict__ out_e,
        int* __restrict__ idx, int* __restrict__ scnt, int* __restrict__ spos,
        int skipTail) {
    __shared__ __align__(16) char smc[38912];
    unsigned short* patchH = (unsigned short*)smc;            // [64][72]
    unsigned short* patchL = (unsigned short*)(smc + 9216);   // [64][72]
    unsigned short* zb = (unsigned short*)(smc + 18432);      // 2 pairs x 5120 shorts

    const int t = threadIdx.x;
    const int bid = blockIdx.x;
    const int q = ((bid & 7) << 6) | (bid >> 3);   // XCD co-location swizzle
    const int P0 = q * 64;
    const int b = P0 >> 10, SP0 = P0 & 1023;
    const int flag = *flagp;
    const int wave = t >> 6, lane = t & 63;
    const int quad = lane >> 4, lcol = lane & 15;

    // stage x patches once as bf16 H/L, K-padded with zeros (q 48..63)
    for (int e = t; e < 4096; e += 512) {
        int pid = e >> 6, qq = e & 63;
        float xv = 0.f;
        if (qq < 48) {
            int c = qq >> 4, r = (qq >> 2) & 3, s = qq & 3;
            int pos = P0 + pid;
            int bb = pos >> 10, sp = pos & 1023, i = sp >> 5, j = sp & 31;
            xv = ldin(x, ((bb * 3 + c) * 128 + (i * 4 + r)) * 128 + (j * 4 + s), flag);
        }
        unsigned short h = f2bf(xv);
        patchH[pid * 72 + qq] = h;
        patchL[pid * 72 + qq] = f2bf(xv - bfu(h));
    }

    floatx4 acc[4][4];
    #pragma unroll
    for (int mt = 0; mt < 4; ++mt)
        #pragma unroll
        for (int j = 0; j < 4; ++j) acc[mt][j] = (floatx4){0.f, 0.f, 0.f, 0.f};

    ldsbar();
    conv_mfma(patchH, patchL, WeswzH, WeswzL, cbe, 0, wave, lane, flag,
              zb, out_z, b, SP0);                             // chunk 0 -> pair 0
    for (int dc = 32; dc < 512; dc += 32) {
        ldsbar();
        const int p = (dc >> 5) & 1;
        conv_mfma(patchH, patchL, WeswzH, WeswzL, cbe, dc, wave, lane, flag,
                  zb + p * 5120, out_z, b, SP0);
        mfma_step(zb + (p ^ 1) * 5120, cbHS, cbLS, dc - 32, wave, quad, lcol, flag, acc);
    }
    ldsbar();
    mfma_step(zb + 5120, cbHS, cbLS, 480, wave, quad, lcol, flag, acc);

    // ---- epilogue: per-lane best/second over its 4 codes, then shuffle ----
    float s1[4][4], s2[4][4]; int k1[4][4];
    #pragma unroll
    for (int mt = 0; mt < 4; ++mt)
        #pragma unroll
        for (int r = 0; r < 4; ++r) { s1[mt][r] = 1e30f; s2[mt][r] = 1e30f; k1[mt][r] = 511; }
    #pragma unroll
    for (int j = 0; j < 4; ++j) {
        int code = (wave * 4 + j) * 16 + lcol;
        float wk = w2[code];
        #pragma unroll
        for (int mt = 0; mt < 4; ++mt)
            #pragma unroll
            for (int r = 0; r < 4; ++r) {
                float s = wk - 2.f * acc[mt][j][r];
                bmerge(s1[mt][r], k1[mt][r], s2[mt][r], s, code, 1e30f);
            }
    }
    // overlay reduction arrays on patchH region (patch dead after last conv+bar)
    float* sS1 = (float*)smc;             // [64 pos][8 wave]
    int*   sK1 = (int*)(smc + 2048);
    float* sS2 = (float*)(smc + 4096);
    int*   ii  = (int*)(smc + 6144);      // [64]
    #pragma unroll
    for (int mt = 0; mt < 4; ++mt)
        #pragma unroll
        for (int r = 0; r < 4; ++r) {
            float a1 = s1[mt][r], a2 = s2[mt][r]; int ak = k1[mt][r];
            #pragma unroll
            for (int m = 1; m < 16; m <<= 1) {
                float o1 = __shfl_xor(a1, m);
                float o2 = __shfl_xor(a2, m);
                int   ok = __shfl_xor(ak, m);
                bmerge(a1, ak, a2, o1, ok, o2);
            }
            if (lcol == 0) {
                int pos = mt * 16 + quad * 4 + r;
                sS1[pos * 8 + wave] = a1;
                sK1[pos * 8 + wave] = ak;
                sS2[pos * 8 + wave] = a2;
            }
        }
    __syncthreads();
    if (t < 64) {
        float a1 = sS1[t * 8]; int ak = sK1[t * 8]; float a2 = sS2[t * 8];
        #pragma unroll
        for (int w = 1; w < 8; ++w)
            bmerge(a1, ak, a2, sS1[t * 8 + w], sK1[t * 8 + w], sS2[t * 8 + w]);
        ak &= 511;
        ii[t] = ak;
        unsigned int flagged = 0u;
        if (a2 - a1 < EPS_GAP) {
            int slot = atomicAdd(scnt, 1);
            if (slot < MAXSUS) { spos[slot] = P0 + t; flagged = 1u; }
        }
        idx[P0 + t] = (int)((unsigned)ak | (flagged << 31));
    }
    __syncthreads();

    // ---- fused emb: out_e[b][d][SP0+sp] = cbT[ii[sp]][d] ----
    const int sp = t & 63, dq = t >> 6;   // 8 groups x 64 d
    const float* row = cbT + (size_t)ii[sp] * 512;
    const size_t obase = ((size_t)b * 512) * 1024 + SP0 + sp;
    for (int d0 = dq * 64; d0 < dq * 64 + 64; d0 += 4) {
        if (skipTail && b == 31 && d0 >= 448) break;
        float4 v = *(const float4*)(row + d0);
        out_e[obase + (size_t)(d0    ) * 1024] = v.x;
        out_e[obase + (size_t)(d0 + 1) * 1024] = v.y;
        out_e[obase + (size_t)(d0 + 2) * 1024] = v.z;
        out_e[obase + (size_t)(d0 + 3) * 1024] = v.w;
    }
}

// ---------------------------------------------------------------------------
// FUSED post: recon (bid 0..127) ∥ rescore (bid 128..383) in one launch.
// ---------------------------------------------------------------------------
__global__ __launch_bounds__(256) void k_post(
        const float* __restrict__ out_z, const void* __restrict__ cb,
        const double* __restrict__ w2d, int* __restrict__ idx,
        const int* __restrict__ scnt, const int* __restrict__ spos,
        const float* __restrict__ U, const int* __restrict__ flagp,
        float* __restrict__ out_e, float* __restrict__ out_r, int skipTail) {
    __shared__ float zsh[512];
    __shared__ float rs[256];
    __shared__ int rk[256];
    __shared__ int bc[2];
    const int bid = blockIdx.x;
    const int t = threadIdx.x;

    if (bid < 128) {
        // ---- recon role ----
        const int pos = bid * 256 + t;
        const int v0 = idx[pos];
        if (v0 >= 0) {
            const int id = v0 & 511;
            const int b = pos >> 10, sp = pos & 1023, i = sp >> 5, j = sp & 31;
            const float* u = &U[(size_t)id * 48];
            #pragma unroll
            for (int c = 0; c < 3; ++c)
                #pragma unroll
                for (int uu = 0; uu < 4; ++uu) {
                    float4 q = *(const float4*)(&u[c * 16 + uu * 4]);
                    float4 o;
                    o.x = 1.f / (1.f + __expf(-q.x));
                    o.y = 1.f / (1.f + __expf(-q.y));
                    o.z = 1.f / (1.f + __expf(-q.z));
                    o.w = 1.f / (1.f + __expf(-q.w));
                    *(float4*)(&out_r[((size_t)((b * 3 + c) * 128) + (i * 4 + uu)) * 128 + j * 4]) = o;
                }
        }
        return;
    }

    // ---- rescore role (256 blocks) ----
    const int flag = *flagp;
    int n = *scnt; if (n > MAXSUS) n = MAXSUS;
    for (int s = bid - 128; s < n; s += 256) {
        int p = spos[s] & 32767;
        int b = p >> 10, sp = p & 1023;
        __syncthreads();
        zsh[t]       = out_z[(size_t)(b * 512 + t) * 1024 + sp];
        zsh[t + 256] = out_z[(size_t)(b * 512 + t + 256) * 1024 + sp];
        __syncthreads();
        float bs = 1e30f; int bk = 511;
        for (int cc = 0; cc < 2; ++cc) {
            int k = t + cc * 256;
            double a = 0.0;
            for (int d = 0; d < 512; ++d)
                a = fma((double)zsh[d], (double)ldin(cb, (size_t)d * 512 + k, flag), a);
            float sc = (float)(w2d[k] - 2.0 * a);
            if (sc < bs || (sc == bs && k < bk)) { bs = sc; bk = k; }
        }
        rs[t] = bs; rk[t] = bk;
        __syncthreads();
        for (int str = 128; str > 0; str >>= 1) {
            if (t < str) {
                float so = rs[t + str]; int ko = rk[t + str];
                if (so < rs[t] || (so == rs[t] && ko < rk[t])) { rs[t] = so; rk[t] = ko; }
            }
            __syncthreads();
        }
        if (t == 0) {
            int kstar = rk[0] & 511;
            int old = idx[p] & 511;
            bc[0] = kstar; bc[1] = (kstar != old);
            idx[p] = kstar;                       // clears suspect flag too
        }
        __syncthreads();
        const int kk = bc[0];
        if (bc[1]) {
            for (int d = t; d < 512; d += 256) {
                if (skipTail && b == 31 && d >= 448) continue;
                out_e[(size_t)(b * 512 + d) * 1024 + sp] = ldin(cb, (size_t)d * 512 + kk, flag);
            }
        }
        // recon for this suspect (recon role skipped it) — always write
        if (t < 48) {
            float q = U[(size_t)kk * 48 + t];
            float o = 1.f / (1.f + __expf(-q));
            int c = t >> 4, uu = (t >> 2) & 3, vv = t & 3;
            int i = sp >> 5, j = sp & 31;
            out_r[((size_t)((b * 3 + c) * 128) + (i * 4 + uu)) * 128 + j * 4 + vv] = o;
        }
    }
}

// ---------------------------------------------------------------------------
// Widened fixup: 64 blocks, one d-row each. Coalesced idx read + row write.
// ---------------------------------------------------------------------------
__global__ __launch_bounds__(1024) void k_fixup(
        const void* __restrict__ cb, const int* __restrict__ flagp,
        const int* __restrict__ idx, float* __restrict__ out_e) {
    const int t = threadIdx.x;
    const int d = 448 + blockIdx.x;
    const int flag = *flagp;
    const int id = idx[31744 + t] & 511;
    out_e[((size_t)(31 * 512 + d)) * 1024 + t] = ldin(cb, (size_t)d * 512 + id, flag);
}

// ---------------------------------------------------------------------------
extern "C" void kernel_launch(void* const* d_in, const int* in_sizes, int n_in,
                              void* d_out, int out_size, void* d_ws, size_t ws_size,
                              hipStream_t stream) {
    const void* x  = d_in[0];
    const void* We = d_in[1];
    const void* be = d_in[2];
    const void* Wd = d_in[3];
    const void* bd = d_in[4];
    const void* cb = d_in[5];

    float* out   = (float*)d_out;
    float* out_r = out;                       // 1,572,864 fp32 (6.29 MB)
    float* out_z = out + 1572864;             // 16,777,216 fp32
    float* out_e = out + 18350080;            // 16,777,216 fp32

    // Read-mostly tables in out_r (recon overwrites during k_post; nothing in
    // k_post reads them — rescore uses raw cb):
    char* Rb = (char*)out_r;
    float* cbT           = (float*)(Rb);                    // 1,048,576 B
    float* cWe           = (float*)(Rb + 1048576);          //    98,304 B
    float* cbe           = (float*)(Rb + 1146880);          //     2,048 B
    float* cWd           = (float*)(Rb + 1148928);          //    98,304 B
    float* cbd           = (float*)(Rb + 1247232);          //        64 B
    unsigned short* cbHS = (unsigned short*)(Rb + 1247296); //   524,288 B (swizzled)
    unsigned short* cbLS = (unsigned short*)(Rb + 1771584); //   524,288 B (swizzled)
    unsigned short* WeswzH=(unsigned short*)(Rb + 2295872); //    65,536 B
    unsigned short* WeswzL=(unsigned short*)(Rb + 2361408); //    65,536 B

    // Tail scratch: prefer d_ws; else last 256 KB of out_e (fixup required).
    int tailWS = (ws_size >= 262144) ? 1 : 0;
    char* Tbase = tailWS ? (char*)d_ws : ((char*)out_e + 66846720);
    int skipTail = tailWS ? 0 : 1;
    int*    idx  = (int*)   (Tbase);            // 131,072 B
    float*  U    = (float*) (Tbase + 131072);   //  98,304 B
    float*  w2   = (float*) (Tbase + 229376);   //   2,048 B
    double* w2d  = (double*)(Tbase + 231424);   //   4,096 B
    int*    flag = (int*)   (Tbase + 235520);   //      64 B
    int*    scnt = (int*)   (Tbase + 235584);   //      64 B
    int*    spos = (int*)   (Tbase + 235648);   //  16,384 B

    k_sniff<<<1, 1024, 0, stream>>>(cb, flag, scnt);
    k_prepAll<<<403, 256, 0, stream>>>(We, be, Wd, bd, cb, flag,
                                       cWe, cbe, cWd, cbd,
                                       cbT, cbHS, cbLS, WeswzH, WeswzL,
                                       w2, w2d, U);
    k_main<<<512, 512, 0, stream>>>(x, WeswzH, WeswzL, cbe, flag, cbHS, cbLS,
                                    cbT, w2, out_z, out_e, idx, scnt, spos,
                                    skipTail);
    k_post<<<384, 256, 0, stream>>>(out_z, cb, w2d, idx, scnt, spos, U, flag,
                                    out_e, out_r, skipTail);
    if (skipTail)
        k_fixup<<<64, 1024, 0, stream>>>(cb, flag, idx, out_e);
}